// Round 4
// baseline (314.850 us; speedup 1.0000x reference)
//
#include <hip/hip_runtime.h>
#include <math.h>

#define L_SEQ 8192
#define B_SZ  2
#define CH    256
#define NLEV  4

typedef __attribute__((ext_vector_type(8))) short bf16x8;
typedef __attribute__((ext_vector_type(4))) float f32x4;

static __device__ __forceinline__ float sigmoidf_(float x) {
    return 1.0f / (1.0f + expf(-x));
}

// bf16 (stored as ushort) <-> fp32 helpers. bf2f is exact; f2b is RNE.
static __device__ __forceinline__ float bf2f_(unsigned short u) {
    union { unsigned int ui; float f; } x;
    x.ui = ((unsigned int)u) << 16;
    return x.f;
}
static __device__ __forceinline__ unsigned short f2b_(float f) {
    union { float f; unsigned int u; } x;
    x.f = f;
    unsigned int lsb = (x.u >> 16) & 1u;
    unsigned int r = x.u + 0x7fffu + lsb;
    return (unsigned short)(r >> 16);
}
static __device__ __forceinline__ float4 ldb4_(const unsigned short* p) {
    ushort4 u = *(const ushort4*)p;
    return make_float4(bf2f_(u.x), bf2f_(u.y), bf2f_(u.z), bf2f_(u.w));
}

// ---------------------------------------------------------------------------
// Fused fp32->bf16 prep: guard row (zeros) + x16 + qkv_w + out_w + stem_w.
// (qw16 rows 512..767 are overwritten by wvp_fold afterwards.)
// ---------------------------------------------------------------------------
__global__ void prep_kernel(const float* __restrict__ x,
                            const float* __restrict__ qkv_w,
                            const float* __restrict__ out_w,
                            const float* __restrict__ stem_w,
                            unsigned short* __restrict__ x16g,
                            unsigned short* __restrict__ qw16,
                            unsigned short* __restrict__ ow16,
                            unsigned short* __restrict__ sw16)
{
    int i = blockIdx.x * 256 + threadIdx.x;
    if (i < 256) { x16g[i] = 0; return; }           // guard row of zeros
    i -= 256;
    if (i < 4194304) { x16g[256 + i] = f2b_(x[i]); return; }
    i -= 4194304;
    if (i < 196608) { qw16[i] = f2b_(qkv_w[i]); return; }
    i -= 196608;
    if (i < 65536) { ow16[i] = f2b_(out_w[i]); return; }
    i -= 65536;
    {   // stem W: (256,512); k<256 -> tap0, else tap1
        int k = i & 511, n = i >> 9;
        float v = (k < 256) ? stem_w[(size_t)n * 512 + k * 2]
                            : stem_w[(size_t)n * 512 + (k - 256) * 2 + 1];
        sw16[i] = f2b_(v);
    }
}

// ---------------------------------------------------------------------------
// Weight fold: W'[c][j] = sum_k out_w[c][k] * qkv_w[512+k][j]  (fp32 acc),
// written into qw16 rows 512..767 (bf16).  This makes the qkv GEMM emit
// Vp = v @ out_w^T directly, so attention's PV output IS the level output:
//   (P @ V_win + v) @ ow^T  ==  P @ Vp_win + Vp.
// ---------------------------------------------------------------------------
__global__ __launch_bounds__(256) void wvp_fold(
    const float* __restrict__ ow, const float* __restrict__ qkvw,
    unsigned short* __restrict__ qw16)
{
    __shared__ float owr[256];
    const int c = blockIdx.x, j = threadIdx.x;
    owr[j] = ow[(size_t)c * 256 + j];
    __syncthreads();
    float acc = 0.0f;
    #pragma unroll 8
    for (int k = 0; k < 256; ++k)
        acc += owr[k] * qkvw[(size_t)(512 + k) * 256 + j];
    qw16[(size_t)(512 + c) * 256 + j] = f2b_(acc);
}

// ---------------------------------------------------------------------------
// Stem conv as MFMA GEMM, staging A directly from x16 (guard row at offset 0,
// row m data at x16g + (m+1)*256). Writes h16 (bias added).
// ---------------------------------------------------------------------------
__global__ __launch_bounds__(256) void stem_gemm_bf16(
    const unsigned short* __restrict__ x16g, const unsigned short* __restrict__ W,
    unsigned short* __restrict__ outB, const float* __restrict__ bias)
{
    __shared__ unsigned short As[128 * 32];
    __shared__ unsigned short Bs[128 * 32];
    const int tid  = threadIdx.x;
    const int wave = tid >> 6;
    const int lane = tid & 63;
    const int bm = blockIdx.y * 128;
    const int bn = blockIdx.x * 128;
    const int wm = (wave & 1) * 64;
    const int wn = (wave >> 1) * 64;
    const int srow = lane >> 2;
    const int scol = (lane & 3) * 8;

    f32x4 acc[4][4] = {};

    for (int k0 = 0; k0 < 512; k0 += 32) {
        __syncthreads();
        #pragma unroll
        for (int c = 0; c < 2; ++c) {
            const int chunk = c * 4 + wave;
            const int row = bm + chunk * 16 + srow;
            const int t = row & (L_SEQ - 1);
            const unsigned short* ga;
            if (k0 < 256)
                ga = x16g + (t > 0 ? (size_t)row * 256 : 0) + k0 + scol;
            else
                ga = x16g + ((size_t)row + 1) * 256 + (k0 - 256) + scol;
            const unsigned short* gw = W + (size_t)(bn + chunk * 16 + srow) * 512 + k0 + scol;
            __builtin_amdgcn_global_load_lds(
                (const __attribute__((address_space(1))) void*)ga,
                (__attribute__((address_space(3))) void*)(As + chunk * 16 * 32),
                16, 0, 0);
            __builtin_amdgcn_global_load_lds(
                (const __attribute__((address_space(1))) void*)gw,
                (__attribute__((address_space(3))) void*)(Bs + chunk * 16 * 32),
                16, 0, 0);
        }
        __syncthreads();

        bf16x8 af[4], bf[4];
        const int fr = lane & 15;
        const int kk = (lane >> 4) * 8;
        #pragma unroll
        for (int i = 0; i < 4; ++i) {
            af[i] = *(const bf16x8*)(As + (wm + i * 16 + fr) * 32 + kk);
            bf[i] = *(const bf16x8*)(Bs + (wn + i * 16 + fr) * 32 + kk);
        }
        #pragma unroll
        for (int i = 0; i < 4; ++i)
            #pragma unroll
            for (int j = 0; j < 4; ++j)
                acc[i][j] = __builtin_amdgcn_mfma_f32_16x16x32_bf16(
                    af[i], bf[j], acc[i][j], 0, 0, 0);
    }

    const int cn = lane & 15;
    const int cr = (lane >> 4) * 4;
    #pragma unroll
    for (int i = 0; i < 4; ++i)
        #pragma unroll
        for (int r = 0; r < 4; ++r) {
            const int m = bm + wm + i * 16 + cr + r;
            #pragma unroll
            for (int j = 0; j < 4; ++j) {
                const int n = bn + wn + j * 16 + cn;
                outB[(size_t)m * CH + n] = f2b_(acc[i][j][r] + bias[n]);
            }
        }
}

// ---------------------------------------------------------------------------
// Generic MFMA bf16 GEMM (m97 structure): out = A @ W^T, bf16 out.
// Used for the qkv projection (N=768, K=256); W rows 512.. hold the folded
// Vp weights, so output cols 512..767 are Vp.
// ---------------------------------------------------------------------------
__global__ __launch_bounds__(256) void gemm_bf16(
    const unsigned short* __restrict__ A, const unsigned short* __restrict__ W,
    unsigned short* __restrict__ outB, int M, int N, int Kd)
{
    __shared__ unsigned short As[128 * 32];
    __shared__ unsigned short Bs[128 * 32];
    const int tid  = threadIdx.x;
    const int wave = tid >> 6;
    const int lane = tid & 63;
    const int bm = blockIdx.y * 128;
    const int bn = blockIdx.x * 128;
    const int wm = (wave & 1) * 64;
    const int wn = (wave >> 1) * 64;
    const int srow = lane >> 2;
    const int scol = (lane & 3) * 8;

    f32x4 acc[4][4] = {};

    for (int k0 = 0; k0 < Kd; k0 += 32) {
        __syncthreads();
        #pragma unroll
        for (int c = 0; c < 2; ++c) {
            const int chunk = c * 4 + wave;
            const int row = chunk * 16 + srow;
            const unsigned short* ga = A + (size_t)(bm + row) * Kd + k0 + scol;
            const unsigned short* gw = W + (size_t)(bn + row) * Kd + k0 + scol;
            __builtin_amdgcn_global_load_lds(
                (const __attribute__((address_space(1))) void*)ga,
                (__attribute__((address_space(3))) void*)(As + chunk * 16 * 32),
                16, 0, 0);
            __builtin_amdgcn_global_load_lds(
                (const __attribute__((address_space(1))) void*)gw,
                (__attribute__((address_space(3))) void*)(Bs + chunk * 16 * 32),
                16, 0, 0);
        }
        __syncthreads();

        bf16x8 af[4], bf[4];
        const int fr = lane & 15;
        const int kk = (lane >> 4) * 8;
        #pragma unroll
        for (int i = 0; i < 4; ++i) {
            af[i] = *(const bf16x8*)(As + (wm + i * 16 + fr) * 32 + kk);
            bf[i] = *(const bf16x8*)(Bs + (wn + i * 16 + fr) * 32 + kk);
        }
        #pragma unroll
        for (int i = 0; i < 4; ++i)
            #pragma unroll
            for (int j = 0; j < 4; ++j)
                acc[i][j] = __builtin_amdgcn_mfma_f32_16x16x32_bf16(
                    af[i], bf[j], acc[i][j], 0, 0, 0);
    }

    const int cn = lane & 15;
    const int cr = (lane >> 4) * 4;
    #pragma unroll
    for (int i = 0; i < 4; ++i)
        #pragma unroll
        for (int r = 0; r < 4; ++r) {
            const int m = bm + wm + i * 16 + cr + r;
            const size_t rowoff = (size_t)m * N;
            #pragma unroll
            for (int j = 0; j < 4; ++j)
                outB[rowoff + bn + wn + j * 16 + cn] = f2b_(acc[i][j][r]);
        }
}

// ---------------------------------------------------------------------------
// Fused local attention (Vp-folded), COLUMN-SPLIT x4 for TLP:
// 1024 threads = 16 waves per 64-row block.  Quartet of waves per 16-row
// tile (rt = wave>>2): all 4 redundantly compute width + QK^T + softmax
// (cheap, and duplicate loads are L1/L2 hits); quartet wave 0 writes P;
// each wave then does ONE QUARTER of PV (4 MFMAs) + stores.  This raises
// occupancy from 1 to 4 waves/SIMD at level 0 — the latency-bound chain
// (scattered K/Q reads, LDS hops) finally overlaps across waves.
// ONE barrier (Vt + P staging).  LDS 49,152 B.
// ---------------------------------------------------------------------------
__global__ __launch_bounds__(1024) void attn_vp_kernel(
    const unsigned short* __restrict__ qkv, const unsigned short* __restrict__ h16,
    const float* __restrict__ ww, const float* __restrict__ wbp,
    unsigned short* __restrict__ l16o, unsigned short* __restrict__ dsB, int l)
{
    __shared__ __align__(16) unsigned short vt[256 * 88];  // Vp^T, 45056 B
    __shared__ __align__(16) unsigned short pb[4 * 512];   // P per row tile

    const int tid  = threadIdx.x;
    const int wave = tid >> 6;
    const int lane = tid & 63;
    const int rt   = wave >> 2;   // row tile 0..3
    const int qt   = wave & 3;    // column quarter 0..3
    const int q    = lane >> 4;
    const int n    = lane & 15;

    // XCD-aware swizzle (grid is always a multiple of 8)
    int bid = blockIdx.x;
    const int cpx = gridDim.x >> 3;
    bid = (bid & 7) * cpx + (bid >> 3);

    const int bps = l >> 6;
    const int b  = bid / bps;
    const int t0 = (bid % bps) << 6;
    const size_t seqbase = (size_t)b * l;
    const int row0 = t0 + rt * 16;

    // ---- issue Vp halo loads FIRST (2560 tasks over 1024 threads) ----
    bf16x8 vval[3];
    #pragma unroll
    for (int i = 0; i < 3; ++i) {
        const int tk = tid + i * 1024;
        bf16x8 val = {0, 0, 0, 0, 0, 0, 0, 0};
        if (tk < 2560) {
            const int r = tk >> 5, ch = tk & 31;
            const int grow = t0 - 8 + r;
            if (grow >= 0 && grow < l)
                val = *(const bf16x8*)(qkv + (seqbase + grow) * 768 + 512 + ch * 8);
        }
        vval[i] = val;
    }

    // ---- fused width head: lane (q,n) accumulates cols [q*64,q*64+64) ----
    float wdot = 0.0f;
    {
        const unsigned short* hrow = h16 + (seqbase + row0 + n) * 256 + q * 64;
        #pragma unroll
        for (int jj = 0; jj < 8; ++jj) {
            bf16x8 hv = *(const bf16x8*)(hrow + jj * 8);
            float4 wa = *((const float4*)(ww + q * 64 + jj * 8));
            float4 wc = *((const float4*)(ww + q * 64 + jj * 8 + 4));
            wdot += bf2f_(((unsigned short*)&hv)[0]) * wa.x
                  + bf2f_(((unsigned short*)&hv)[1]) * wa.y
                  + bf2f_(((unsigned short*)&hv)[2]) * wa.z
                  + bf2f_(((unsigned short*)&hv)[3]) * wa.w
                  + bf2f_(((unsigned short*)&hv)[4]) * wc.x
                  + bf2f_(((unsigned short*)&hv)[5]) * wc.y
                  + bf2f_(((unsigned short*)&hv)[6]) * wc.z
                  + bf2f_(((unsigned short*)&hv)[7]) * wc.w;
        }
    }
    wdot += __shfl_xor(wdot, 16, 64);
    wdot += __shfl_xor(wdot, 32, 64);
    const float w_n = sigmoidf_(wdot + wbp[0]) * 8.0f + 0.5f;  // width of row n

    // ---- Q A-fragments straight from global ----
    bf16x8 qf[8];
    const unsigned short* qrow = qkv + (seqbase + row0 + n) * 768;
    #pragma unroll
    for (int kk = 0; kk < 8; ++kk)
        qf[kk] = *(const bf16x8*)(qrow + kk * 32 + q * 8);

    // ---- QK^T: B-fragments directly from global (masked at seq edges) ----
    f32x4 accS[2] = {};
    __builtin_amdgcn_s_setprio(1);
    #pragma unroll
    for (int h = 0; h < 2; ++h) {
        const int grow = row0 - 8 + h * 16 + n;
        const bool ok = (grow >= 0 && grow < l);
        const unsigned short* kb = qkv + (seqbase + grow) * 768 + 256 + q * 8;
        #pragma unroll
        for (int kk = 0; kk < 8; ++kk) {
            bf16x8 bk = {0, 0, 0, 0, 0, 0, 0, 0};
            if (ok) bk = *(const bf16x8*)(kb + kk * 32);
            accS[h] = __builtin_amdgcn_mfma_f32_16x16x32_bf16(
                qf[kk], bk, accS[h], 0, 0, 0);
        }
    }
    __builtin_amdgcn_s_setprio(0);

    // ---- scatter Vp halo into vt (transposed) ----
    #pragma unroll
    for (int i = 0; i < 3; ++i) {
        const int tk = tid + i * 1024;
        if (tk < 2560) {
            const int r = tk >> 5, ch = tk & 31;
            #pragma unroll
            for (int jj = 0; jj < 8; ++jj)
                vt[(ch * 8 + jj) * 88 + r] = ((unsigned short*)&vval[i])[jj];
        }
    }

    // widths for this lane's 4 C-layout rows (ii = q*4+r), pulled via shfl
    float wd[4];
    #pragma unroll
    for (int r = 0; r < 4; ++r) wd[r] = __shfl(w_n, q * 4 + r, 64);

    // mask + scale (C-layout: col c = h*16+n, row ii = q*4+r)
    float s[2][4];
    #pragma unroll
    for (int h = 0; h < 2; ++h)
        #pragma unroll
        for (int r = 0; r < 4; ++r) {
            int ii = q * 4 + r;
            int c  = h * 16 + n;
            int w  = c - ii;
            float dist = fabsf((float)w - 8.0f);
            float sm = sigmoidf_((wd[r] - dist) * 5.0f);
            float v = accS[h][r] * 0.0625f - (1.0f - sm) * 10000.0f;
            s[h][r] = (w >= 0 && w <= 16) ? v : -3.0e38f;
        }

    // softmax over the row (16 lanes of the quad hold the 32 cols)
    float mx[4], sum[4];
    #pragma unroll
    for (int r = 0; r < 4; ++r) mx[r] = fmaxf(s[0][r], s[1][r]);
    #pragma unroll
    for (int m = 1; m < 16; m <<= 1)
        #pragma unroll
        for (int r = 0; r < 4; ++r) mx[r] = fmaxf(mx[r], __shfl_xor(mx[r], m, 64));
    float e[2][4];
    #pragma unroll
    for (int h = 0; h < 2; ++h)
        #pragma unroll
        for (int r = 0; r < 4; ++r) e[h][r] = expf(s[h][r] - mx[r]);
    #pragma unroll
    for (int r = 0; r < 4; ++r) sum[r] = e[0][r] + e[1][r];
    #pragma unroll
    for (int m = 1; m < 16; m <<= 1)
        #pragma unroll
        for (int r = 0; r < 4; ++r) sum[r] += __shfl_xor(sum[r], m, 64);

    // quartet wave 0 writes P (bf16), folding the +Vp[t] residual (+1 at
    // center col c == ii+8)
    if (qt == 0) {
        #pragma unroll
        for (int h = 0; h < 2; ++h)
            #pragma unroll
            for (int r = 0; r < 4; ++r) {
                int ii = q * 4 + r, c = h * 16 + n;
                float p = e[h][r] / sum[r];
                if (c == ii + 8) p += 1.0f;
                pb[rt * 512 + ii * 32 + c] = f2b_(p);
            }
    }

    __syncthreads();  // Vt + P fully staged

    // ---- PV quarter: chunks qt*4 .. qt*4+3; output IS the level output ----
    bf16x8 pf = *(const bf16x8*)(pb + rt * 512 + n * 32 + q * 8);
    const int rl = q * 4;                       // even
    const size_t gbase = seqbase + row0;
    __builtin_amdgcn_s_setprio(1);
    f32x4 po[4];
    #pragma unroll
    for (int c = 0; c < 4; ++c) {
        const int ct = qt * 4 + c;
        bf16x8 vf = *(const bf16x8*)(vt + (ct * 16 + n) * 88 + rt * 16 + q * 8);
        f32x4 z = {};
        po[c] = __builtin_amdgcn_mfma_f32_16x16x32_bf16(pf, vf, z, 0, 0, 0);
    }
    __builtin_amdgcn_s_setprio(0);
    #pragma unroll
    for (int c = 0; c < 4; ++c) {
        const int ct = qt * 4 + c;
        const int col = ct * 16 + n;
        float v0 = po[c][0], v1 = po[c][1], v2 = po[c][2], v3 = po[c][3];
        size_t r0 = (gbase + rl) * CH + col;
        l16o[r0]          = f2b_(v0);
        l16o[r0 + CH]     = f2b_(v1);
        l16o[r0 + 2 * CH] = f2b_(v2);
        l16o[r0 + 3 * CH] = f2b_(v3);
        if (dsB) {
            size_t d0 = ((gbase + rl) >> 1) * CH + col;
            dsB[d0]      = f2b_(0.5f * (v0 + v1));
            dsB[d0 + CH] = f2b_(0.5f * (v2 + v3));
        }
    }
}

// ---------------------------------------------------------------------------
// Fused global-attention tail: per block (chunk of 128 t's, batch b):
//   pass 1: e[t] = exp(concat[t]·query)  (unnormalized softmax — |s| small)
//   pass 2: partials[d] = sum_t e[t]*concat[t][d]; denomP = sum_t e[t]
// grid (64, B), block 1024.
// ---------------------------------------------------------------------------
__global__ __launch_bounds__(1024) void tail_ctx_kernel(
    const unsigned short* __restrict__ l0, const unsigned short* __restrict__ l1,
    const unsigned short* __restrict__ l2, const unsigned short* __restrict__ l3,
    const float* __restrict__ query, float* __restrict__ partials,
    float* __restrict__ denomP)
{
    __shared__ float eS[128];
    const int tid = threadIdx.x;
    const int chunk = blockIdx.x, b = blockIdx.y;
    const int t0 = chunk * 128;
    const unsigned short* levp[4] = {l0, l1, l2, l3};

    // ---- pass 1: wave w computes e for t = t0 + w*8 + j ----
    const int w = tid >> 6, lane = tid & 63;
    const int lev = lane >> 4, c0 = (lane & 15) * 16;
    const unsigned short* lpbase = levp[lev] + (size_t)b * (L_SEQ >> lev) * CH;
    const float* qp = query + lev * CH + c0;
    float4 q0 = *(const float4*)(qp);
    float4 q1 = *(const float4*)(qp + 4);
    float4 q2 = *(const float4*)(qp + 8);
    float4 q3 = *(const float4*)(qp + 12);
    #pragma unroll
    for (int j = 0; j < 8; ++j) {
        int t = t0 + w * 8 + j;
        const unsigned short* p = lpbase + (size_t)(t >> lev) * CH + c0;
        float4 h0 = ldb4_(p), h1 = ldb4_(p + 4), h2 = ldb4_(p + 8), h3 = ldb4_(p + 12);
        float part = h0.x * q0.x + h0.y * q0.y + h0.z * q0.z + h0.w * q0.w
                   + h1.x * q1.x + h1.y * q1.y + h1.z * q1.z + h1.w * q1.w
                   + h2.x * q2.x + h2.y * q2.y + h2.z * q2.z + h2.w * q2.w
                   + h3.x * q3.x + h3.y * q3.y + h3.z * q3.z + h3.w * q3.w;
        #pragma unroll
        for (int m = 1; m < 64; m <<= 1) part += __shfl_xor(part, m, 64);
        if (lane == 0) eS[w * 8 + j] = expf(part);
    }
    __syncthreads();

    if (tid == 0) {
        float ds = 0.0f;
        #pragma unroll 8
        for (int i = 0; i < 128; ++i) ds += eS[i];
        denomP[b * 64 + chunk] = ds;
    }

    // ---- pass 2: weighted accumulation (rows are L2-hot from pass 1) ----
    const int dlev = tid >> 8, c = tid & 255;
    const unsigned short* lp = levp[dlev] + (size_t)b * (L_SEQ >> dlev) * CH;
    float acc = 0.0f;
    #pragma unroll 4
    for (int t = t0; t < t0 + 128; ++t)
        acc += eS[t - t0] * bf2f_(lp[(size_t)(t >> dlev) * CH + c]);
    partials[(size_t)(b * 64 + chunk) * 1024 + tid] = acc;
}

// grid (4, B), block 256: ctx[b*1024+d] = (sum over 64 chunks) / denom
__global__ __launch_bounds__(256) void ctx_reduce_kernel(
    const float* __restrict__ partials, const float* __restrict__ denomP,
    float* __restrict__ ctx)
{
    const int b = blockIdx.y;
    const int d = blockIdx.x * 256 + threadIdx.x;
    float acc = 0.0f;
    #pragma unroll
    for (int c = 0; c < 64; ++c) acc += partials[(size_t)(b * 64 + c) * 1024 + d];
    float den = 0.0f;
    #pragma unroll
    for (int c = 0; c < 64; ++c) den += denomP[b * 64 + c];
    ctx[b * 1024 + d] = acc / den;
}

// film[b,j] = ctx[b,:]·fw[j,:] + fb[j]. One wave per j, both batches.
__global__ __launch_bounds__(256) void film_kernel(
    const float* __restrict__ ctx, const float* __restrict__ fw,
    const float* __restrict__ fb, float* __restrict__ film)
{
    const int lane = threadIdx.x & 63;
    const int j = blockIdx.x * 4 + (threadIdx.x >> 6);  // 0..511
    float acc0 = 0.0f, acc1 = 0.0f;
    #pragma unroll
    for (int r = 0; r < 4; ++r) {
        float4 w4 = *((const float4*)(fw + (size_t)j * 1024 + r * 256) + lane);
        float4 c0 = *((const float4*)(ctx + r * 256) + lane);
        float4 c1 = *((const float4*)(ctx + 1024 + r * 256) + lane);
        acc0 += w4.x * c0.x + w4.y * c0.y + w4.z * c0.z + w4.w * c0.w;
        acc1 += w4.x * c1.x + w4.y * c1.y + w4.z * c1.z + w4.w * c1.w;
    }
    #pragma unroll
    for (int m = 1; m < 64; m <<= 1) {
        acc0 += __shfl_xor(acc0, m, 64);
        acc1 += __shfl_xor(acc1, m, 64);
    }
    if (lane == 0) {
        float b = fb[j];
        film[j] = acc0 + b;
        film[512 + j] = acc1 + b;
    }
}

// out = l16_0 * (1 + scale_f) + bias_f, 4 elem/thread (ushort4 -> float4)
__global__ void final_kernel(const unsigned short* __restrict__ lev0,
                             const float* __restrict__ film,
                             float* __restrict__ out)
{
    size_t n4 = ((size_t)blockIdx.x * 256 + threadIdx.x) * 4;
    int c = (int)(n4 & (CH - 1));
    int b = (int)(n4 >> 21);  // L*C = 2^21
    float4 h = ldb4_(lev0 + n4);
    const float* fs = film + b * 512;
    float4 o;
    o.x = h.x * (1.0f + fs[c + 0]) + fs[256 + c + 0];
    o.y = h.y * (1.0f + fs[c + 1]) + fs[256 + c + 1];
    o.z = h.z * (1.0f + fs[c + 2]) + fs[256 + c + 2];
    o.w = h.w * (1.0f + fs[c + 3]) + fs[256 + c + 3];
    *(float4*)(out + n4) = o;
}

extern "C" void kernel_launch(void* const* d_in, const int* in_sizes, int n_in,
                              void* d_out, int out_size, void* d_ws, size_t ws_size,
                              hipStream_t stream) {
    const float* x       = (const float*)d_in[0];
    const float* stem_w  = (const float*)d_in[1];
    const float* stem_b  = (const float*)d_in[2];
    const float* qkv_w   = (const float*)d_in[3];
    const float* width_w = (const float*)d_in[4];
    const float* width_b = (const float*)d_in[5];
    const float* out_w   = (const float*)d_in[6];
    const float* query   = (const float*)d_in[7];
    const float* film_w  = (const float*)d_in[8];
    const float* film_b  = (const float*)d_in[9];
    float* out = (float*)d_out;
    float* ws  = (float*)d_ws;

    // ---- workspace layout (fp32 region then bf16 region) ----
    float* partials = ws;                       // 131,072
    float* denomP   = partials + 131072;        // 128
    float* ctx      = denomP + 128;             // 2,048
    float* film     = ctx + 2048;               // 1,024
    unsigned short* x16g  = (unsigned short*)(film + 1024);  // 256 guard + 4,194,304
    unsigned short* h16_0 = x16g + 4194560;     // 4,194,304
    unsigned short* h16_1 = h16_0 + 4194304;    // 2,097,152
    unsigned short* h16_2 = h16_1 + 2097152;    // 1,048,576
    unsigned short* h16_3 = h16_2 + 1048576;    //   524,288
    unsigned short* qkv16 = h16_3 + 524288;     // 12,582,912
    unsigned short* ov16  = qkv16 + 12582912;   // 4,194,304 (reserved, unused)
    unsigned short* l16_0 = ov16 + 4194304;     // 4,194,304
    unsigned short* l16_1 = l16_0 + 4194304;    // 2,097,152
    unsigned short* l16_2 = l16_1 + 2097152;    // 1,048,576
    unsigned short* l16_3 = l16_2 + 1048576;    //   524,288
    unsigned short* qw16  = l16_3 + 524288;     //   196,608
    unsigned short* ow16  = qw16 + 196608;      //    65,536
    unsigned short* sw16  = ow16 + 65536;       //   131,072
    unsigned short* h16[4]  = {h16_0, h16_1, h16_2, h16_3};
    unsigned short* l16[4]  = {l16_0, l16_1, l16_2, l16_3};
    (void)ov16;

    // ---- fused prep (guard + x16 + all weights) ----
    prep_kernel<<<(256 + 4194304 + 196608 + 65536 + 131072) / 256, 256, 0, stream>>>(
        x, qkv_w, out_w, stem_w, x16g, qw16, ow16, sw16);

    // ---- fold out_w into the v rows of the qkv weights (Vp = v @ ow^T) ----
    wvp_fold<<<256, 256, 0, stream>>>(out_w, qkv_w, qw16);

    // ---- stem conv as bf16 GEMM (A staged directly from x16) ----
    stem_gemm_bf16<<<dim3(CH / 128, B_SZ * L_SEQ / 128), 256, 0, stream>>>(
        x16g, sw16, h16_0, stem_b);

    // ---- hierarchy levels: qkv GEMM (q,k,Vp) + fused attn (col-split x4) --
    for (int i = 0; i < NLEV; ++i) {
        const int l = L_SEQ >> i;
        const int M = B_SZ * l;
        gemm_bf16<<<dim3(768 / 128, M / 128), 256, 0, stream>>>(
            h16[i], qw16, qkv16, M, 768, CH);
        attn_vp_kernel<<<M / 64, 1024, 0, stream>>>(
            qkv16, h16[i], width_w, width_b,
            l16[i], (i < NLEV - 1) ? h16[i + 1] : nullptr, l);
    }

    // ---- fused global-attention tail + FiLM ----
    tail_ctx_kernel<<<dim3(64, B_SZ), 1024, 0, stream>>>(
        l16_0, l16_1, l16_2, l16_3, query, partials, denomP);
    ctx_reduce_kernel<<<dim3(4, B_SZ), 256, 0, stream>>>(partials, denomP, ctx);
    film_kernel<<<128, 256, 0, stream>>>(ctx, film_w, film_b, film);
    final_kernel<<<(B_SZ * L_SEQ * CH) / 1024, 256, 0, stream>>>(l16_0, film, out);
}

// Round 5
// 248.987 us; speedup vs baseline: 1.2645x; 1.2645x over previous
//
#include <hip/hip_runtime.h>
#include <math.h>

#define L_SEQ 8192
#define B_SZ  2
#define CH    256
#define NLEV  4

typedef __attribute__((ext_vector_type(8))) short bf16x8;
typedef __attribute__((ext_vector_type(4))) float f32x4;

static __device__ __forceinline__ float sigmoidf_(float x) {
    return 1.0f / (1.0f + expf(-x));
}

// bf16 (stored as ushort) <-> fp32 helpers. bf2f is exact; f2b is RNE.
static __device__ __forceinline__ float bf2f_(unsigned short u) {
    union { unsigned int ui; float f; } x;
    x.ui = ((unsigned int)u) << 16;
    return x.f;
}
static __device__ __forceinline__ unsigned short f2b_(float f) {
    union { float f; unsigned int u; } x;
    x.f = f;
    unsigned int lsb = (x.u >> 16) & 1u;
    unsigned int r = x.u + 0x7fffu + lsb;
    return (unsigned short)(r >> 16);
}
static __device__ __forceinline__ float4 ldb4_(const unsigned short* p) {
    ushort4 u = *(const ushort4*)p;
    return make_float4(bf2f_(u.x), bf2f_(u.y), bf2f_(u.z), bf2f_(u.w));
}

// ---------------------------------------------------------------------------
// Fused fp32->bf16 prep + weight fold, one launch:
//   blocks [0, 17409):   guard row + x16 + qkv_w rows 0..511 + stem_w
//   blocks [17409, 17665): W'[c][j] = sum_k out_w[c][k]*qkv_w[512+k][j]
//     -> qw16 rows 512..767 (bf16).  This makes the qkv GEMM emit
//     Vp = v @ out_w^T, so attention's PV output IS the level output:
//     (P @ V_win + v) @ ow^T == P @ Vp_win + Vp.
// No race: elementwise blocks write qw16 rows 0..511 only.
// ---------------------------------------------------------------------------
#define NPREP_BLOCKS 17409
__global__ __launch_bounds__(256) void prep_kernel(
    const float* __restrict__ x, const float* __restrict__ qkv_w,
    const float* __restrict__ out_w, const float* __restrict__ stem_w,
    unsigned short* __restrict__ x16g, unsigned short* __restrict__ qw16,
    unsigned short* __restrict__ sw16)
{
    __shared__ float owr[256];
    if (blockIdx.x >= NPREP_BLOCKS) {
        const int c = blockIdx.x - NPREP_BLOCKS, j = threadIdx.x;
        owr[j] = out_w[(size_t)c * 256 + j];
        __syncthreads();
        float acc = 0.0f;
        #pragma unroll 8
        for (int k = 0; k < 256; ++k)
            acc += owr[k] * qkv_w[(size_t)(512 + k) * 256 + j];
        qw16[(size_t)(512 + c) * 256 + j] = f2b_(acc);
        return;
    }
    int i = blockIdx.x * 256 + threadIdx.x;
    if (i < 256) { x16g[i] = 0; return; }           // guard row of zeros
    i -= 256;
    if (i < 4194304) { x16g[256 + i] = f2b_(x[i]); return; }
    i -= 4194304;
    if (i < 131072) { qw16[i] = f2b_(qkv_w[i]); return; }  // q,k rows only
    i -= 131072;
    {   // stem W: (256,512); k<256 -> tap0, else tap1
        int k = i & 511, nn = i >> 9;
        float v = (k < 256) ? stem_w[(size_t)nn * 512 + k * 2]
                            : stem_w[(size_t)nn * 512 + (k - 256) * 2 + 1];
        sw16[i] = f2b_(v);
    }
}

// ---------------------------------------------------------------------------
// Stem conv as MFMA GEMM, staging A directly from x16 (guard row at offset 0,
// row m data at x16g + (m+1)*256). Writes h16 (bias added).
// ---------------------------------------------------------------------------
__global__ __launch_bounds__(256) void stem_gemm_bf16(
    const unsigned short* __restrict__ x16g, const unsigned short* __restrict__ W,
    unsigned short* __restrict__ outB, const float* __restrict__ bias)
{
    __shared__ unsigned short As[128 * 32];
    __shared__ unsigned short Bs[128 * 32];
    const int tid  = threadIdx.x;
    const int wave = tid >> 6;
    const int lane = tid & 63;
    const int bm = blockIdx.y * 128;
    const int bn = blockIdx.x * 128;
    const int wm = (wave & 1) * 64;
    const int wn = (wave >> 1) * 64;
    const int srow = lane >> 2;
    const int scol = (lane & 3) * 8;

    f32x4 acc[4][4] = {};

    for (int k0 = 0; k0 < 512; k0 += 32) {
        __syncthreads();
        #pragma unroll
        for (int c = 0; c < 2; ++c) {
            const int chunk = c * 4 + wave;
            const int row = bm + chunk * 16 + srow;
            const int t = row & (L_SEQ - 1);
            const unsigned short* ga;
            if (k0 < 256)
                ga = x16g + (t > 0 ? (size_t)row * 256 : 0) + k0 + scol;
            else
                ga = x16g + ((size_t)row + 1) * 256 + (k0 - 256) + scol;
            const unsigned short* gw = W + (size_t)(bn + chunk * 16 + srow) * 512 + k0 + scol;
            __builtin_amdgcn_global_load_lds(
                (const __attribute__((address_space(1))) void*)ga,
                (__attribute__((address_space(3))) void*)(As + chunk * 16 * 32),
                16, 0, 0);
            __builtin_amdgcn_global_load_lds(
                (const __attribute__((address_space(1))) void*)gw,
                (__attribute__((address_space(3))) void*)(Bs + chunk * 16 * 32),
                16, 0, 0);
        }
        __syncthreads();

        bf16x8 af[4], bf[4];
        const int fr = lane & 15;
        const int kk = (lane >> 4) * 8;
        #pragma unroll
        for (int i = 0; i < 4; ++i) {
            af[i] = *(const bf16x8*)(As + (wm + i * 16 + fr) * 32 + kk);
            bf[i] = *(const bf16x8*)(Bs + (wn + i * 16 + fr) * 32 + kk);
        }
        #pragma unroll
        for (int i = 0; i < 4; ++i)
            #pragma unroll
            for (int j = 0; j < 4; ++j)
                acc[i][j] = __builtin_amdgcn_mfma_f32_16x16x32_bf16(
                    af[i], bf[j], acc[i][j], 0, 0, 0);
    }

    const int cn = lane & 15;
    const int cr = (lane >> 4) * 4;
    #pragma unroll
    for (int i = 0; i < 4; ++i)
        #pragma unroll
        for (int r = 0; r < 4; ++r) {
            const int m = bm + wm + i * 16 + cr + r;
            #pragma unroll
            for (int j = 0; j < 4; ++j) {
                const int n = bn + wn + j * 16 + cn;
                outB[(size_t)m * CH + n] = f2b_(acc[i][j][r] + bias[n]);
            }
        }
}

// ---------------------------------------------------------------------------
// Generic MFMA bf16 GEMM (m97 structure): out = A @ W^T, bf16 out.
// Used for the qkv projection (N=768, K=256); W rows 512.. hold the folded
// Vp weights, so output cols 512..767 are Vp.
// ---------------------------------------------------------------------------
__global__ __launch_bounds__(256) void gemm_bf16(
    const unsigned short* __restrict__ A, const unsigned short* __restrict__ W,
    unsigned short* __restrict__ outB, int M, int N, int Kd)
{
    __shared__ unsigned short As[128 * 32];
    __shared__ unsigned short Bs[128 * 32];
    const int tid  = threadIdx.x;
    const int wave = tid >> 6;
    const int lane = tid & 63;
    const int bm = blockIdx.y * 128;
    const int bn = blockIdx.x * 128;
    const int wm = (wave & 1) * 64;
    const int wn = (wave >> 1) * 64;
    const int srow = lane >> 2;
    const int scol = (lane & 3) * 8;

    f32x4 acc[4][4] = {};

    for (int k0 = 0; k0 < Kd; k0 += 32) {
        __syncthreads();
        #pragma unroll
        for (int c = 0; c < 2; ++c) {
            const int chunk = c * 4 + wave;
            const int row = chunk * 16 + srow;
            const unsigned short* ga = A + (size_t)(bm + row) * Kd + k0 + scol;
            const unsigned short* gw = W + (size_t)(bn + row) * Kd + k0 + scol;
            __builtin_amdgcn_global_load_lds(
                (const __attribute__((address_space(1))) void*)ga,
                (__attribute__((address_space(3))) void*)(As + chunk * 16 * 32),
                16, 0, 0);
            __builtin_amdgcn_global_load_lds(
                (const __attribute__((address_space(1))) void*)gw,
                (__attribute__((address_space(3))) void*)(Bs + chunk * 16 * 32),
                16, 0, 0);
        }
        __syncthreads();

        bf16x8 af[4], bf[4];
        const int fr = lane & 15;
        const int kk = (lane >> 4) * 8;
        #pragma unroll
        for (int i = 0; i < 4; ++i) {
            af[i] = *(const bf16x8*)(As + (wm + i * 16 + fr) * 32 + kk);
            bf[i] = *(const bf16x8*)(Bs + (wn + i * 16 + fr) * 32 + kk);
        }
        #pragma unroll
        for (int i = 0; i < 4; ++i)
            #pragma unroll
            for (int j = 0; j < 4; ++j)
                acc[i][j] = __builtin_amdgcn_mfma_f32_16x16x32_bf16(
                    af[i], bf[j], acc[i][j], 0, 0, 0);
    }

    const int cn = lane & 15;
    const int cr = (lane >> 4) * 4;
    #pragma unroll
    for (int i = 0; i < 4; ++i)
        #pragma unroll
        for (int r = 0; r < 4; ++r) {
            const int m = bm + wm + i * 16 + cr + r;
            const size_t rowoff = (size_t)m * N;
            #pragma unroll
            for (int j = 0; j < 4; ++j)
                outB[rowoff + bn + wn + j * 16 + cn] = f2b_(acc[i][j][r]);
        }
}

// ---------------------------------------------------------------------------
// Fused local attention (Vp-folded), REG-BATCHED loads:
// 4 waves x 16 rows = 64 rows/block; ONE barrier (Vt staging).
// All ~42 global loads (h16 width inputs, Q, K, Vp halo) are issued into
// register arrays up front (sched_barrier-pinned), so the wave pays ONE
// memory latency instead of ~20 serialized ones — the critical fix for a
// structurally 1-wave/SIMD kernel (waves = rows/16).
// LDS: Vt[256][88] (45 KB) + pb 4x[16][32] (4 KB) = 49 KB.
// ---------------------------------------------------------------------------
__global__ __launch_bounds__(256, 1) void attn_vp_kernel(
    const unsigned short* __restrict__ qkv, const unsigned short* __restrict__ h16,
    const float* __restrict__ ww, const float* __restrict__ wbp,
    unsigned short* __restrict__ l16o, unsigned short* __restrict__ dsB, int l)
{
    __shared__ __align__(16) unsigned short vt[256 * 88];  // Vp^T, 45056 B
    __shared__ __align__(16) unsigned short pb[4 * 512];   // P per wave

    const int tid  = threadIdx.x;
    const int wave = tid >> 6;
    const int lane = tid & 63;
    const int q    = lane >> 4;
    const int n    = lane & 15;

    // XCD-aware swizzle (grid is always a multiple of 8)
    int bid = blockIdx.x;
    const int cpx = gridDim.x >> 3;
    bid = (bid & 7) * cpx + (bid >> 3);

    const int bps = l >> 6;
    const int b  = bid / bps;
    const int t0 = (bid % bps) << 6;
    const size_t seqbase = (size_t)b * l;
    const int row0 = t0 + wave * 16;

    // ======== batched load issue: hv, qf, bk, vval all in flight ========
    bf16x8 hv[8];
    {
        const unsigned short* hrow = h16 + (seqbase + row0 + n) * 256 + q * 64;
        #pragma unroll
        for (int jj = 0; jj < 8; ++jj) hv[jj] = *(const bf16x8*)(hrow + jj * 8);
    }
    bf16x8 qf[8];
    {
        const unsigned short* qrow = qkv + (seqbase + row0 + n) * 768 + q * 8;
        #pragma unroll
        for (int kk = 0; kk < 8; ++kk) qf[kk] = *(const bf16x8*)(qrow + kk * 32);
    }
    bf16x8 bk[2][8];
    #pragma unroll
    for (int h = 0; h < 2; ++h) {
        const int grow = row0 - 8 + h * 16 + n;
        const bool ok = (grow >= 0 && grow < l);
        const unsigned short* kb = qkv + (seqbase + grow) * 768 + 256 + q * 8;
        #pragma unroll
        for (int kk = 0; kk < 8; ++kk) {
            bf16x8 z = {0, 0, 0, 0, 0, 0, 0, 0};
            bk[h][kk] = ok ? *(const bf16x8*)(kb + kk * 32) : z;
        }
    }
    bf16x8 vval[10];
    {
        const int r = tid & 15;
        const int ch0 = tid >> 4;
        #pragma unroll
        for (int p5 = 0; p5 < 5; ++p5)
            #pragma unroll
            for (int cc = 0; cc < 2; ++cc) {
                const int grow = t0 - 8 + p5 * 16 + r;
                bf16x8 val = {0, 0, 0, 0, 0, 0, 0, 0};
                if (grow >= 0 && grow < l)
                    val = *(const bf16x8*)(qkv + (seqbase + grow) * 768 + 512 +
                                           (cc * 16 + ch0) * 8);
                vval[p5 * 2 + cc] = val;
            }
    }
    __builtin_amdgcn_sched_barrier(0);   // pin: all loads issued above this

    // ======== width head (consumes hv; first vmcnt wait lands here) ========
    float wdot = 0.0f;
    #pragma unroll
    for (int jj = 0; jj < 8; ++jj) {
        float4 wa = *((const float4*)(ww + q * 64 + jj * 8));
        float4 wc = *((const float4*)(ww + q * 64 + jj * 8 + 4));
        wdot += bf2f_((unsigned short)hv[jj][0]) * wa.x
              + bf2f_((unsigned short)hv[jj][1]) * wa.y
              + bf2f_((unsigned short)hv[jj][2]) * wa.z
              + bf2f_((unsigned short)hv[jj][3]) * wa.w
              + bf2f_((unsigned short)hv[jj][4]) * wc.x
              + bf2f_((unsigned short)hv[jj][5]) * wc.y
              + bf2f_((unsigned short)hv[jj][6]) * wc.z
              + bf2f_((unsigned short)hv[jj][7]) * wc.w;
    }
    wdot += __shfl_xor(wdot, 16, 64);
    wdot += __shfl_xor(wdot, 32, 64);
    const float w_n = sigmoidf_(wdot + wbp[0]) * 8.0f + 0.5f;  // width of row n

    // ======== QK^T from registers ========
    f32x4 accS[2] = {};
    #pragma unroll
    for (int h = 0; h < 2; ++h)
        #pragma unroll
        for (int kk = 0; kk < 8; ++kk)
            accS[h] = __builtin_amdgcn_mfma_f32_16x16x32_bf16(
                qf[kk], bk[h][kk], accS[h], 0, 0, 0);

    // widths for this lane's 4 C-layout rows (ii = q*4+r), pulled via shfl
    float wd[4];
    #pragma unroll
    for (int r = 0; r < 4; ++r) wd[r] = __shfl(w_n, q * 4 + r, 64);

    // mask + scale (C-layout: col c = h*16+n, row ii = q*4+r)
    float s[2][4];
    #pragma unroll
    for (int h = 0; h < 2; ++h)
        #pragma unroll
        for (int r = 0; r < 4; ++r) {
            int ii = q * 4 + r;
            int c  = h * 16 + n;
            int w  = c - ii;
            float dist = fabsf((float)w - 8.0f);
            float sm = sigmoidf_((wd[r] - dist) * 5.0f);
            float v = accS[h][r] * 0.0625f - (1.0f - sm) * 10000.0f;
            s[h][r] = (w >= 0 && w <= 16) ? v : -3.0e38f;
        }

    // softmax over the row (16 lanes of the quad hold the 32 cols)
    float mx[4], sum[4];
    #pragma unroll
    for (int r = 0; r < 4; ++r) mx[r] = fmaxf(s[0][r], s[1][r]);
    #pragma unroll
    for (int m = 1; m < 16; m <<= 1)
        #pragma unroll
        for (int r = 0; r < 4; ++r) mx[r] = fmaxf(mx[r], __shfl_xor(mx[r], m, 64));
    float e[2][4];
    #pragma unroll
    for (int h = 0; h < 2; ++h)
        #pragma unroll
        for (int r = 0; r < 4; ++r) e[h][r] = expf(s[h][r] - mx[r]);
    #pragma unroll
    for (int r = 0; r < 4; ++r) sum[r] = e[0][r] + e[1][r];
    #pragma unroll
    for (int m = 1; m < 16; m <<= 1)
        #pragma unroll
        for (int r = 0; r < 4; ++r) sum[r] += __shfl_xor(sum[r], m, 64);

    // write P (bf16, wave-local), folding the +Vp[t] residual: +1 at c==ii+8
    #pragma unroll
    for (int h = 0; h < 2; ++h)
        #pragma unroll
        for (int r = 0; r < 4; ++r) {
            int ii = q * 4 + r, c = h * 16 + n;
            float p = e[h][r] / sum[r];
            if (c == ii + 8) p += 1.0f;
            pb[wave * 512 + ii * 32 + c] = f2b_(p);
        }

    // ======== scatter Vp halo into vt (transposed); vval long arrived ======
    {
        const int r = tid & 15;
        const int ch0 = tid >> 4;
        #pragma unroll
        for (int p5 = 0; p5 < 5; ++p5)
            #pragma unroll
            for (int cc = 0; cc < 2; ++cc) {
                const int rr = p5 * 16 + r;
                const int chunk = cc * 16 + ch0;
                #pragma unroll
                for (int jj = 0; jj < 8; ++jj)
                    vt[(chunk * 8 + jj) * 88 + rr] =
                        (unsigned short)vval[p5 * 2 + cc][jj];
            }
    }

    __syncthreads();  // Vt fully staged (P is wave-local)

    // ---- PV: A = P (A-layout), B = Vt slices; output IS the level output --
    bf16x8 pf = *(const bf16x8*)(pb + wave * 512 + n * 32 + q * 8);
    const int rl = q * 4;                       // even
    const size_t gbase = seqbase + row0;
    #pragma unroll
    for (int ct = 0; ct < 16; ++ct) {
        bf16x8 vf = *(const bf16x8*)(vt + (ct * 16 + n) * 88 + wave * 16 + q * 8);
        f32x4 z = {};
        f32x4 o = __builtin_amdgcn_mfma_f32_16x16x32_bf16(pf, vf, z, 0, 0, 0);
        const int col = ct * 16 + n;
        float v0 = o[0], v1 = o[1], v2 = o[2], v3 = o[3];
        size_t r0 = (gbase + rl) * CH + col;
        l16o[r0]          = f2b_(v0);
        l16o[r0 + CH]     = f2b_(v1);
        l16o[r0 + 2 * CH] = f2b_(v2);
        l16o[r0 + 3 * CH] = f2b_(v3);
        if (dsB) {
            size_t d0 = ((gbase + rl) >> 1) * CH + col;
            dsB[d0]      = f2b_(0.5f * (v0 + v1));
            dsB[d0 + CH] = f2b_(0.5f * (v2 + v3));
        }
    }
}

// ---------------------------------------------------------------------------
// Fused global-attention tail: per block (chunk of 128 t's, batch b):
//   pass 1: e[t] = exp(concat[t]·query)  (unnormalized softmax — |s| small)
//   pass 2: partials[d] = sum_t e[t]*concat[t][d]; denomP = sum_t e[t]
// grid (64, B), block 1024.
// ---------------------------------------------------------------------------
__global__ __launch_bounds__(1024) void tail_ctx_kernel(
    const unsigned short* __restrict__ l0, const unsigned short* __restrict__ l1,
    const unsigned short* __restrict__ l2, const unsigned short* __restrict__ l3,
    const float* __restrict__ query, float* __restrict__ partials,
    float* __restrict__ denomP)
{
    __shared__ float eS[128];
    const int tid = threadIdx.x;
    const int chunk = blockIdx.x, b = blockIdx.y;
    const int t0 = chunk * 128;
    const unsigned short* levp[4] = {l0, l1, l2, l3};

    // ---- pass 1: wave w computes e for t = t0 + w*8 + j ----
    const int w = tid >> 6, lane = tid & 63;
    const int lev = lane >> 4, c0 = (lane & 15) * 16;
    const unsigned short* lpbase = levp[lev] + (size_t)b * (L_SEQ >> lev) * CH;
    const float* qp = query + lev * CH + c0;
    float4 q0 = *(const float4*)(qp);
    float4 q1 = *(const float4*)(qp + 4);
    float4 q2 = *(const float4*)(qp + 8);
    float4 q3 = *(const float4*)(qp + 12);
    #pragma unroll
    for (int j = 0; j < 8; ++j) {
        int t = t0 + w * 8 + j;
        const unsigned short* p = lpbase + (size_t)(t >> lev) * CH + c0;
        float4 h0 = ldb4_(p), h1 = ldb4_(p + 4), h2 = ldb4_(p + 8), h3 = ldb4_(p + 12);
        float part = h0.x * q0.x + h0.y * q0.y + h0.z * q0.z + h0.w * q0.w
                   + h1.x * q1.x + h1.y * q1.y + h1.z * q1.z + h1.w * q1.w
                   + h2.x * q2.x + h2.y * q2.y + h2.z * q2.z + h2.w * q2.w
                   + h3.x * q3.x + h3.y * q3.y + h3.z * q3.z + h3.w * q3.w;
        #pragma unroll
        for (int m = 1; m < 64; m <<= 1) part += __shfl_xor(part, m, 64);
        if (lane == 0) eS[w * 8 + j] = expf(part);
    }
    __syncthreads();

    if (tid == 0) {
        float ds = 0.0f;
        #pragma unroll 8
        for (int i = 0; i < 128; ++i) ds += eS[i];
        denomP[b * 64 + chunk] = ds;
    }

    // ---- pass 2: weighted accumulation (rows are L2-hot from pass 1) ----
    const int dlev = tid >> 8, c = tid & 255;
    const unsigned short* lp = levp[dlev] + (size_t)b * (L_SEQ >> dlev) * CH;
    float acc = 0.0f;
    #pragma unroll 4
    for (int t = t0; t < t0 + 128; ++t)
        acc += eS[t - t0] * bf2f_(lp[(size_t)(t >> dlev) * CH + c]);
    partials[(size_t)(b * 64 + chunk) * 1024 + tid] = acc;
}

// grid (4, B), block 256: ctx[b*1024+d] = (sum over 64 chunks) / denom
__global__ __launch_bounds__(256) void ctx_reduce_kernel(
    const float* __restrict__ partials, const float* __restrict__ denomP,
    float* __restrict__ ctx)
{
    const int b = blockIdx.y;
    const int d = blockIdx.x * 256 + threadIdx.x;
    float acc = 0.0f;
    #pragma unroll
    for (int c = 0; c < 64; ++c) acc += partials[(size_t)(b * 64 + c) * 1024 + d];
    float den = 0.0f;
    #pragma unroll
    for (int c = 0; c < 64; ++c) den += denomP[b * 64 + c];
    ctx[b * 1024 + d] = acc / den;
}

// film[b,j] = ctx[b,:]·fw[j,:] + fb[j]. One wave per j, both batches.
__global__ __launch_bounds__(256) void film_kernel(
    const float* __restrict__ ctx, const float* __restrict__ fw,
    const float* __restrict__ fb, float* __restrict__ film)
{
    const int lane = threadIdx.x & 63;
    const int j = blockIdx.x * 4 + (threadIdx.x >> 6);  // 0..511
    float acc0 = 0.0f, acc1 = 0.0f;
    #pragma unroll
    for (int r = 0; r < 4; ++r) {
        float4 w4 = *((const float4*)(fw + (size_t)j * 1024 + r * 256) + lane);
        float4 c0 = *((const float4*)(ctx + r * 256) + lane);
        float4 c1 = *((const float4*)(ctx + 1024 + r * 256) + lane);
        acc0 += w4.x * c0.x + w4.y * c0.y + w4.z * c0.z + w4.w * c0.w;
        acc1 += w4.x * c1.x + w4.y * c1.y + w4.z * c1.z + w4.w * c1.w;
    }
    #pragma unroll
    for (int m = 1; m < 64; m <<= 1) {
        acc0 += __shfl_xor(acc0, m, 64);
        acc1 += __shfl_xor(acc1, m, 64);
    }
    if (lane == 0) {
        float b = fb[j];
        film[j] = acc0 + b;
        film[512 + j] = acc1 + b;
    }
}

// out = l16_0 * (1 + scale_f) + bias_f, 4 elem/thread (ushort4 -> float4)
__global__ void final_kernel(const unsigned short* __restrict__ lev0,
                             const float* __restrict__ film,
                             float* __restrict__ out)
{
    size_t n4 = ((size_t)blockIdx.x * 256 + threadIdx.x) * 4;
    int c = (int)(n4 & (CH - 1));
    int b = (int)(n4 >> 21);  // L*C = 2^21
    float4 h = ldb4_(lev0 + n4);
    const float* fs = film + b * 512;
    float4 o;
    o.x = h.x * (1.0f + fs[c + 0]) + fs[256 + c + 0];
    o.y = h.y * (1.0f + fs[c + 1]) + fs[256 + c + 1];
    o.z = h.z * (1.0f + fs[c + 2]) + fs[256 + c + 2];
    o.w = h.w * (1.0f + fs[c + 3]) + fs[256 + c + 3];
    *(float4*)(out + n4) = o;
}

extern "C" void kernel_launch(void* const* d_in, const int* in_sizes, int n_in,
                              void* d_out, int out_size, void* d_ws, size_t ws_size,
                              hipStream_t stream) {
    const float* x       = (const float*)d_in[0];
    const float* stem_w  = (const float*)d_in[1];
    const float* stem_b  = (const float*)d_in[2];
    const float* qkv_w   = (const float*)d_in[3];
    const float* width_w = (const float*)d_in[4];
    const float* width_b = (const float*)d_in[5];
    const float* out_w   = (const float*)d_in[6];
    const float* query   = (const float*)d_in[7];
    const float* film_w  = (const float*)d_in[8];
    const float* film_b  = (const float*)d_in[9];
    float* out = (float*)d_out;
    float* ws  = (float*)d_ws;

    // ---- workspace layout (fp32 region then bf16 region) ----
    float* partials = ws;                       // 131,072
    float* denomP   = partials + 131072;        // 128
    float* ctx      = denomP + 128;             // 2,048
    float* film     = ctx + 2048;               // 1,024
    unsigned short* x16g  = (unsigned short*)(film + 1024);  // 256 guard + 4,194,304
    unsigned short* h16_0 = x16g + 4194560;     // 4,194,304
    unsigned short* h16_1 = h16_0 + 4194304;    // 2,097,152
    unsigned short* h16_2 = h16_1 + 2097152;    // 1,048,576
    unsigned short* h16_3 = h16_2 + 1048576;    //   524,288
    unsigned short* qkv16 = h16_3 + 524288;     // 12,582,912
    unsigned short* ov16  = qkv16 + 12582912;   // 4,194,304 (reserved, unused)
    unsigned short* l16_0 = ov16 + 4194304;     // 4,194,304
    unsigned short* l16_1 = l16_0 + 4194304;    // 2,097,152
    unsigned short* l16_2 = l16_1 + 2097152;    // 1,048,576
    unsigned short* l16_3 = l16_2 + 1048576;    //   524,288
    unsigned short* qw16  = l16_3 + 524288;     //   196,608
    unsigned short* ow16  = qw16 + 196608;      //    65,536 (reserved, unused)
    unsigned short* sw16  = ow16 + 65536;       //   131,072
    unsigned short* h16[4]  = {h16_0, h16_1, h16_2, h16_3};
    unsigned short* l16[4]  = {l16_0, l16_1, l16_2, l16_3};
    (void)ov16; (void)ow16;

    // ---- fused prep (guard + x16 + q/k weights + stem) + Vp weight fold ----
    prep_kernel<<<NPREP_BLOCKS + 256, 256, 0, stream>>>(
        x, qkv_w, out_w, stem_w, x16g, qw16, sw16);

    // ---- stem conv as bf16 GEMM (A staged directly from x16) ----
    stem_gemm_bf16<<<dim3(CH / 128, B_SZ * L_SEQ / 128), 256, 0, stream>>>(
        x16g, sw16, h16_0, stem_b);

    // ---- hierarchy levels: qkv GEMM (q,k,Vp) + fused attn (reg-batched) ----
    for (int i = 0; i < NLEV; ++i) {
        const int l = L_SEQ >> i;
        const int M = B_SZ * l;
        gemm_bf16<<<dim3(768 / 128, M / 128), 256, 0, stream>>>(
            h16[i], qw16, qkv16, M, 768, CH);
        attn_vp_kernel<<<M / 64, 256, 0, stream>>>(
            qkv16, h16[i], width_w, width_b,
            l16[i], (i < NLEV - 1) ? h16[i + 1] : nullptr, l);
    }

    // ---- fused global-attention tail + FiLM ----
    tail_ctx_kernel<<<dim3(64, B_SZ), 1024, 0, stream>>>(
        l16_0, l16_1, l16_2, l16_3, query, partials, denomP);
    ctx_reduce_kernel<<<dim3(4, B_SZ), 256, 0, stream>>>(partials, denomP, ctx);
    film_kernel<<<128, 256, 0, stream>>>(ctx, film_w, film_b, film);
    final_kernel<<<(B_SZ * L_SEQ * CH) / 1024, 256, 0, stream>>>(l16_0, film, out);
}

// Round 6
// 241.303 us; speedup vs baseline: 1.3048x; 1.0318x over previous
//
#include <hip/hip_runtime.h>
#include <math.h>

#define L_SEQ 8192
#define B_SZ  2
#define CH    256
#define NLEV  4

typedef __attribute__((ext_vector_type(8))) short bf16x8;
typedef __attribute__((ext_vector_type(4))) float f32x4;

static __device__ __forceinline__ float sigmoidf_(float x) {
    return 1.0f / (1.0f + expf(-x));
}

// bf16 (stored as ushort) <-> fp32 helpers. bf2f is exact; f2b is RNE.
static __device__ __forceinline__ float bf2f_(unsigned short u) {
    union { unsigned int ui; float f; } x;
    x.ui = ((unsigned int)u) << 16;
    return x.f;
}
static __device__ __forceinline__ unsigned short f2b_(float f) {
    union { float f; unsigned int u; } x;
    x.f = f;
    unsigned int lsb = (x.u >> 16) & 1u;
    unsigned int r = x.u + 0x7fffu + lsb;
    return (unsigned short)(r >> 16);
}
static __device__ __forceinline__ float4 ldb4_(const unsigned short* p) {
    ushort4 u = *(const ushort4*)p;
    return make_float4(bf2f_(u.x), bf2f_(u.y), bf2f_(u.z), bf2f_(u.w));
}

// ---------------------------------------------------------------------------
// Fused fp32->bf16 prep + weight fold, one launch:
//   blocks [0, 17409):   guard row + x16 + qkv_w rows 0..511 + stem_w
//   blocks [17409, 17665): W'[c][j] = sum_k out_w[c][k]*qkv_w[512+k][j]
//     -> qw16 rows 512..767 (bf16).  Vp = v @ out_w^T, so attention's PV
//     output IS the level output: (P@V_win + v)@ow^T == P@Vp_win + Vp.
// ---------------------------------------------------------------------------
#define NPREP_BLOCKS 17409
__global__ __launch_bounds__(256) void prep_kernel(
    const float* __restrict__ x, const float* __restrict__ qkv_w,
    const float* __restrict__ out_w, const float* __restrict__ stem_w,
    unsigned short* __restrict__ x16g, unsigned short* __restrict__ qw16,
    unsigned short* __restrict__ sw16)
{
    __shared__ float owr[256];
    if (blockIdx.x >= NPREP_BLOCKS) {
        const int c = blockIdx.x - NPREP_BLOCKS, j = threadIdx.x;
        owr[j] = out_w[(size_t)c * 256 + j];
        __syncthreads();
        float acc = 0.0f;
        #pragma unroll 8
        for (int k = 0; k < 256; ++k)
            acc += owr[k] * qkv_w[(size_t)(512 + k) * 256 + j];
        qw16[(size_t)(512 + c) * 256 + j] = f2b_(acc);
        return;
    }
    int i = blockIdx.x * 256 + threadIdx.x;
    if (i < 256) { x16g[i] = 0; return; }           // guard row of zeros
    i -= 256;
    if (i < 4194304) { x16g[256 + i] = f2b_(x[i]); return; }
    i -= 4194304;
    if (i < 131072) { qw16[i] = f2b_(qkv_w[i]); return; }  // q,k rows only
    i -= 131072;
    {   // stem W: (256,512); k<256 -> tap0, else tap1
        int k = i & 511, nn = i >> 9;
        float v = (k < 256) ? stem_w[(size_t)nn * 512 + k * 2]
                            : stem_w[(size_t)nn * 512 + (k - 256) * 2 + 1];
        sw16[i] = f2b_(v);
    }
}

// ---------------------------------------------------------------------------
// Stem conv as MFMA GEMM, staging A directly from x16 (guard row at offset 0,
// row m data at x16g + (m+1)*256). Writes h16 (bias added).
// ---------------------------------------------------------------------------
__global__ __launch_bounds__(256) void stem_gemm_bf16(
    const unsigned short* __restrict__ x16g, const unsigned short* __restrict__ W,
    unsigned short* __restrict__ outB, const float* __restrict__ bias)
{
    __shared__ unsigned short As[128 * 32];
    __shared__ unsigned short Bs[128 * 32];
    const int tid  = threadIdx.x;
    const int wave = tid >> 6;
    const int lane = tid & 63;
    const int bm = blockIdx.y * 128;
    const int bn = blockIdx.x * 128;
    const int wm = (wave & 1) * 64;
    const int wn = (wave >> 1) * 64;
    const int srow = lane >> 2;
    const int scol = (lane & 3) * 8;

    f32x4 acc[4][4] = {};

    for (int k0 = 0; k0 < 512; k0 += 32) {
        __syncthreads();
        #pragma unroll
        for (int c = 0; c < 2; ++c) {
            const int chunk = c * 4 + wave;
            const int row = bm + chunk * 16 + srow;
            const int t = row & (L_SEQ - 1);
            const unsigned short* ga;
            if (k0 < 256)
                ga = x16g + (t > 0 ? (size_t)row * 256 : 0) + k0 + scol;
            else
                ga = x16g + ((size_t)row + 1) * 256 + (k0 - 256) + scol;
            const unsigned short* gw = W + (size_t)(bn + chunk * 16 + srow) * 512 + k0 + scol;
            __builtin_amdgcn_global_load_lds(
                (const __attribute__((address_space(1))) void*)ga,
                (__attribute__((address_space(3))) void*)(As + chunk * 16 * 32),
                16, 0, 0);
            __builtin_amdgcn_global_load_lds(
                (const __attribute__((address_space(1))) void*)gw,
                (__attribute__((address_space(3))) void*)(Bs + chunk * 16 * 32),
                16, 0, 0);
        }
        __syncthreads();

        bf16x8 af[4], bf[4];
        const int fr = lane & 15;
        const int kk = (lane >> 4) * 8;
        #pragma unroll
        for (int i = 0; i < 4; ++i) {
            af[i] = *(const bf16x8*)(As + (wm + i * 16 + fr) * 32 + kk);
            bf[i] = *(const bf16x8*)(Bs + (wn + i * 16 + fr) * 32 + kk);
        }
        #pragma unroll
        for (int i = 0; i < 4; ++i)
            #pragma unroll
            for (int j = 0; j < 4; ++j)
                acc[i][j] = __builtin_amdgcn_mfma_f32_16x16x32_bf16(
                    af[i], bf[j], acc[i][j], 0, 0, 0);
    }

    const int cn = lane & 15;
    const int cr = (lane >> 4) * 4;
    #pragma unroll
    for (int i = 0; i < 4; ++i)
        #pragma unroll
        for (int r = 0; r < 4; ++r) {
            const int m = bm + wm + i * 16 + cr + r;
            #pragma unroll
            for (int j = 0; j < 4; ++j) {
                const int n = bn + wn + j * 16 + cn;
                outB[(size_t)m * CH + n] = f2b_(acc[i][j][r] + bias[n]);
            }
        }
}

// ---------------------------------------------------------------------------
// Generic MFMA bf16 GEMM (m97 structure): out = A @ W^T, bf16 out.
// Used for the qkv projection (N=768, K=256); W rows 512.. hold the folded
// Vp weights, so output cols 512..767 are Vp.
// ---------------------------------------------------------------------------
__global__ __launch_bounds__(256) void gemm_bf16(
    const unsigned short* __restrict__ A, const unsigned short* __restrict__ W,
    unsigned short* __restrict__ outB, int M, int N, int Kd)
{
    __shared__ unsigned short As[128 * 32];
    __shared__ unsigned short Bs[128 * 32];
    const int tid  = threadIdx.x;
    const int wave = tid >> 6;
    const int lane = tid & 63;
    const int bm = blockIdx.y * 128;
    const int bn = blockIdx.x * 128;
    const int wm = (wave & 1) * 64;
    const int wn = (wave >> 1) * 64;
    const int srow = lane >> 2;
    const int scol = (lane & 3) * 8;

    f32x4 acc[4][4] = {};

    for (int k0 = 0; k0 < Kd; k0 += 32) {
        __syncthreads();
        #pragma unroll
        for (int c = 0; c < 2; ++c) {
            const int chunk = c * 4 + wave;
            const int row = chunk * 16 + srow;
            const unsigned short* ga = A + (size_t)(bm + row) * Kd + k0 + scol;
            const unsigned short* gw = W + (size_t)(bn + row) * Kd + k0 + scol;
            __builtin_amdgcn_global_load_lds(
                (const __attribute__((address_space(1))) void*)ga,
                (__attribute__((address_space(3))) void*)(As + chunk * 16 * 32),
                16, 0, 0);
            __builtin_amdgcn_global_load_lds(
                (const __attribute__((address_space(1))) void*)gw,
                (__attribute__((address_space(3))) void*)(Bs + chunk * 16 * 32),
                16, 0, 0);
        }
        __syncthreads();

        bf16x8 af[4], bf[4];
        const int fr = lane & 15;
        const int kk = (lane >> 4) * 8;
        #pragma unroll
        for (int i = 0; i < 4; ++i) {
            af[i] = *(const bf16x8*)(As + (wm + i * 16 + fr) * 32 + kk);
            bf[i] = *(const bf16x8*)(Bs + (wn + i * 16 + fr) * 32 + kk);
        }
        #pragma unroll
        for (int i = 0; i < 4; ++i)
            #pragma unroll
            for (int j = 0; j < 4; ++j)
                acc[i][j] = __builtin_amdgcn_mfma_f32_16x16x32_bf16(
                    af[i], bf[j], acc[i][j], 0, 0, 0);
    }

    const int cn = lane & 15;
    const int cr = (lane >> 4) * 4;
    #pragma unroll
    for (int i = 0; i < 4; ++i)
        #pragma unroll
        for (int r = 0; r < 4; ++r) {
            const int m = bm + wm + i * 16 + cr + r;
            const size_t rowoff = (size_t)m * N;
            #pragma unroll
            for (int j = 0; j < 4; ++j)
                outB[rowoff + bn + wn + j * 16 + cn] = f2b_(acc[i][j][r]);
        }
}

// ---------------------------------------------------------------------------
// Fused local attention (Vp-folded), K-SPLIT x2 + conflict-free Vt scatter:
// 512 threads = 8 waves, 64 rows/block.  Wave (rt = w&3, half = w>>2):
//   - loads HALF the channels of h16/Q/K (no duplication) -> 2x waves/SIMD
//   - computes partial QK^T over its 128 channels; half-1 parks partial S
//     (fp32) + width partial in LDS; barrier; half-0 combines + softmax +
//     writes P; barrier; PV split by column halves (8 MFMAs each).
//   - Vt scatter: each wave owns 4 channel-chunks, lanes sweep CONSECUTIVE
//     halo rows -> every ds_write_b16 instruction hits 64 consecutive
//     shorts (<=2-way bank aliasing, free) instead of the old 32-way
//     same-bank pattern.
// LDS: vt 45,056 + sp1 8,192 + pb 4,096 + ws1 256 = 57,600 B.
// ---------------------------------------------------------------------------
__global__ __launch_bounds__(512, 2) void attn_vp_kernel(
    const unsigned short* __restrict__ qkv, const unsigned short* __restrict__ h16,
    const float* __restrict__ ww, const float* __restrict__ wbp,
    unsigned short* __restrict__ l16o, unsigned short* __restrict__ dsB, int l)
{
    __shared__ __align__(16) unsigned short vt[256 * 88];  // Vp^T
    __shared__ __align__(16) float sp1[4 * 2 * 64 * 4];    // half-1 partial S
    __shared__ __align__(16) unsigned short pb[4 * 512];   // P per row tile
    __shared__ float ws1[64];                              // half-1 width part

    const int tid  = threadIdx.x;
    const int wave = tid >> 6;
    const int lane = tid & 63;
    const int rt   = wave & 3;    // row tile 0..3
    const int half = wave >> 2;   // channel half 0..1
    const int q    = lane >> 4;
    const int n    = lane & 15;

    // XCD-aware swizzle (grid is always a multiple of 8)
    int bid = blockIdx.x;
    const int cpx = gridDim.x >> 3;
    bid = (bid & 7) * cpx + (bid >> 3);

    const int bps = l >> 6;
    const int b  = bid / bps;
    const int t0 = (bid % bps) << 6;
    const size_t seqbase = (size_t)b * l;
    const int row0 = t0 + rt * 16;
    const int kc0  = half * 128;       // channel base for this half

    // ======== batched global load issue (consumption order) ========
    bf16x8 hv[4];
    {
        const unsigned short* hrow = h16 + (seqbase + row0 + n) * 256 + kc0 + q * 32;
        #pragma unroll
        for (int jj = 0; jj < 4; ++jj) hv[jj] = *(const bf16x8*)(hrow + jj * 8);
    }
    bf16x8 qf[4];
    {
        const unsigned short* qrow = qkv + (seqbase + row0 + n) * 768 + kc0 + q * 8;
        #pragma unroll
        for (int j = 0; j < 4; ++j) qf[j] = *(const bf16x8*)(qrow + j * 32);
    }
    bf16x8 bk[2][4];
    #pragma unroll
    for (int h = 0; h < 2; ++h) {
        const int grow = row0 - 8 + h * 16 + n;
        const bool ok = (grow >= 0 && grow < l);
        const unsigned short* kb = qkv + (seqbase + grow) * 768 + 256 + kc0 + q * 8;
        #pragma unroll
        for (int j = 0; j < 4; ++j) {
            bf16x8 z = {0, 0, 0, 0, 0, 0, 0, 0};
            bk[h][j] = ok ? *(const bf16x8*)(kb + j * 32) : z;
        }
    }
    // Vp halo: wave owns channel chunks [wave*4, wave*4+4); lane sweeps rows
    bf16x8 vv[8];
    #pragma unroll
    for (int c = 0; c < 4; ++c)
        #pragma unroll
        for (int i = 0; i < 2; ++i) {
            const int r = i * 64 + lane;
            const int grow = t0 - 8 + r;
            bf16x8 val = {0, 0, 0, 0, 0, 0, 0, 0};
            if (r < 80 && grow >= 0 && grow < l)
                val = *(const bf16x8*)(qkv + (seqbase + grow) * 768 + 512 +
                                       (wave * 4 + c) * 8);
            vv[c * 2 + i] = val;
        }
    __builtin_amdgcn_sched_barrier(0);   // pin: all loads issued above

    // ======== width head partial (32 channels per lane) ========
    float wdot = 0.0f;
    #pragma unroll
    for (int jj = 0; jj < 4; ++jj) {
        float4 wa = *((const float4*)(ww + kc0 + q * 32 + jj * 8));
        float4 wc = *((const float4*)(ww + kc0 + q * 32 + jj * 8 + 4));
        wdot += bf2f_((unsigned short)hv[jj][0]) * wa.x
              + bf2f_((unsigned short)hv[jj][1]) * wa.y
              + bf2f_((unsigned short)hv[jj][2]) * wa.z
              + bf2f_((unsigned short)hv[jj][3]) * wa.w
              + bf2f_((unsigned short)hv[jj][4]) * wc.x
              + bf2f_((unsigned short)hv[jj][5]) * wc.y
              + bf2f_((unsigned short)hv[jj][6]) * wc.z
              + bf2f_((unsigned short)hv[jj][7]) * wc.w;
    }
    wdot += __shfl_xor(wdot, 16, 64);
    wdot += __shfl_xor(wdot, 32, 64);     // per-n half-sum in every lane
    if (half == 1 && q == 0) ws1[rt * 16 + n] = wdot;

    // ======== QK^T partial (4 k-chunks of this half) ========
    f32x4 accS[2] = {};
    #pragma unroll
    for (int h = 0; h < 2; ++h)
        #pragma unroll
        for (int j = 0; j < 4; ++j)
            accS[h] = __builtin_amdgcn_mfma_f32_16x16x32_bf16(
                qf[j], bk[h][j], accS[h], 0, 0, 0);

    if (half == 1) {
        *(f32x4*)(sp1 + ((rt * 2 + 0) * 64 + lane) * 4) = accS[0];
        *(f32x4*)(sp1 + ((rt * 2 + 1) * 64 + lane) * 4) = accS[1];
    }

    // ======== Vt scatter: consecutive-r per instruction (conflict-free) ====
    #pragma unroll
    for (int c = 0; c < 4; ++c)
        #pragma unroll
        for (int i = 0; i < 2; ++i) {
            const int r = i * 64 + lane;
            if (i == 0 || lane < 16) {
                #pragma unroll
                for (int jj = 0; jj < 8; ++jj)
                    vt[((wave * 4 + c) * 8 + jj) * 88 + r] =
                        (unsigned short)vv[c * 2 + i][jj];
            }
        }

    __syncthreads();   // barrier 1: sp1 + ws1 + vt staged

    if (half == 0) {
        // combine S halves (chain(k0..3) + chain(k4..7)) and width halves
        accS[0] += *(const f32x4*)(sp1 + ((rt * 2 + 0) * 64 + lane) * 4);
        accS[1] += *(const f32x4*)(sp1 + ((rt * 2 + 1) * 64 + lane) * 4);
        const float w_n = sigmoidf_(wdot + ws1[rt * 16 + n] + wbp[0]) * 8.0f + 0.5f;

        float wd[4];
        #pragma unroll
        for (int r = 0; r < 4; ++r) wd[r] = __shfl(w_n, q * 4 + r, 64);

        float s[2][4];
        #pragma unroll
        for (int h = 0; h < 2; ++h)
            #pragma unroll
            for (int r = 0; r < 4; ++r) {
                int ii = q * 4 + r;
                int c  = h * 16 + n;
                int w  = c - ii;
                float dist = fabsf((float)w - 8.0f);
                float sm = sigmoidf_((wd[r] - dist) * 5.0f);
                float v = accS[h][r] * 0.0625f - (1.0f - sm) * 10000.0f;
                s[h][r] = (w >= 0 && w <= 16) ? v : -3.0e38f;
            }

        float mx[4], sum[4];
        #pragma unroll
        for (int r = 0; r < 4; ++r) mx[r] = fmaxf(s[0][r], s[1][r]);
        #pragma unroll
        for (int m = 1; m < 16; m <<= 1)
            #pragma unroll
            for (int r = 0; r < 4; ++r) mx[r] = fmaxf(mx[r], __shfl_xor(mx[r], m, 64));
        float e[2][4];
        #pragma unroll
        for (int h = 0; h < 2; ++h)
            #pragma unroll
            for (int r = 0; r < 4; ++r) e[h][r] = expf(s[h][r] - mx[r]);
        #pragma unroll
        for (int r = 0; r < 4; ++r) sum[r] = e[0][r] + e[1][r];
        #pragma unroll
        for (int m = 1; m < 16; m <<= 1)
            #pragma unroll
            for (int r = 0; r < 4; ++r) sum[r] += __shfl_xor(sum[r], m, 64);

        // write P (bf16), folding the +Vp[t] residual: +1 at center c == ii+8
        #pragma unroll
        for (int h = 0; h < 2; ++h)
            #pragma unroll
            for (int r = 0; r < 4; ++r) {
                int ii = q * 4 + r, c = h * 16 + n;
                float p = e[h][r] / sum[r];
                if (c == ii + 8) p += 1.0f;
                pb[rt * 512 + ii * 32 + c] = f2b_(p);
            }
    }

    __syncthreads();   // barrier 2: P visible to both halves

    // ======== PV: this wave handles ct = half*8 .. half*8+7 ========
    bf16x8 pf = *(const bf16x8*)(pb + rt * 512 + n * 32 + q * 8);
    const int rl = q * 4;                       // even
    const size_t gbase = seqbase + row0;
    #pragma unroll
    for (int c = 0; c < 8; ++c) {
        const int ct = half * 8 + c;
        bf16x8 vf = *(const bf16x8*)(vt + (ct * 16 + n) * 88 + rt * 16 + q * 8);
        f32x4 z = {};
        f32x4 o = __builtin_amdgcn_mfma_f32_16x16x32_bf16(pf, vf, z, 0, 0, 0);
        const int col = ct * 16 + n;
        float v0 = o[0], v1 = o[1], v2 = o[2], v3 = o[3];
        size_t r0 = (gbase + rl) * CH + col;
        l16o[r0]          = f2b_(v0);
        l16o[r0 + CH]     = f2b_(v1);
        l16o[r0 + 2 * CH] = f2b_(v2);
        l16o[r0 + 3 * CH] = f2b_(v3);
        if (dsB) {
            size_t d0 = ((gbase + rl) >> 1) * CH + col;
            dsB[d0]      = f2b_(0.5f * (v0 + v1));
            dsB[d0 + CH] = f2b_(0.5f * (v2 + v3));
        }
    }
}

// ---------------------------------------------------------------------------
// Fused global-attention tail: per block (chunk of 128 t's, batch b):
//   pass 1: e[t] = exp(concat[t]·query)  (unnormalized softmax — |s| small)
//   pass 2: partials[d] = sum_t e[t]*concat[t][d]; denomP = sum_t e[t]
// grid (64, B), block 1024.
// ---------------------------------------------------------------------------
__global__ __launch_bounds__(1024) void tail_ctx_kernel(
    const unsigned short* __restrict__ l0, const unsigned short* __restrict__ l1,
    const unsigned short* __restrict__ l2, const unsigned short* __restrict__ l3,
    const float* __restrict__ query, float* __restrict__ partials,
    float* __restrict__ denomP)
{
    __shared__ float eS[128];
    const int tid = threadIdx.x;
    const int chunk = blockIdx.x, b = blockIdx.y;
    const int t0 = chunk * 128;
    const unsigned short* levp[4] = {l0, l1, l2, l3};

    // ---- pass 1: wave w computes e for t = t0 + w*8 + j ----
    const int w = tid >> 6, lane = tid & 63;
    const int lev = lane >> 4, c0 = (lane & 15) * 16;
    const unsigned short* lpbase = levp[lev] + (size_t)b * (L_SEQ >> lev) * CH;
    const float* qp = query + lev * CH + c0;
    float4 q0 = *(const float4*)(qp);
    float4 q1 = *(const float4*)(qp + 4);
    float4 q2 = *(const float4*)(qp + 8);
    float4 q3 = *(const float4*)(qp + 12);
    #pragma unroll
    for (int j = 0; j < 8; ++j) {
        int t = t0 + w * 8 + j;
        const unsigned short* p = lpbase + (size_t)(t >> lev) * CH + c0;
        float4 h0 = ldb4_(p), h1 = ldb4_(p + 4), h2 = ldb4_(p + 8), h3 = ldb4_(p + 12);
        float part = h0.x * q0.x + h0.y * q0.y + h0.z * q0.z + h0.w * q0.w
                   + h1.x * q1.x + h1.y * q1.y + h1.z * q1.z + h1.w * q1.w
                   + h2.x * q2.x + h2.y * q2.y + h2.z * q2.z + h2.w * q2.w
                   + h3.x * q3.x + h3.y * q3.y + h3.z * q3.z + h3.w * q3.w;
        #pragma unroll
        for (int m = 1; m < 64; m <<= 1) part += __shfl_xor(part, m, 64);
        if (lane == 0) eS[w * 8 + j] = expf(part);
    }
    __syncthreads();

    if (tid == 0) {
        float ds = 0.0f;
        #pragma unroll 8
        for (int i = 0; i < 128; ++i) ds += eS[i];
        denomP[b * 64 + chunk] = ds;
    }

    // ---- pass 2: weighted accumulation (rows are L2-hot from pass 1) ----
    const int dlev = tid >> 8, c = tid & 255;
    const unsigned short* lp = levp[dlev] + (size_t)b * (L_SEQ >> dlev) * CH;
    float acc = 0.0f;
    #pragma unroll 4
    for (int t = t0; t < t0 + 128; ++t)
        acc += eS[t - t0] * bf2f_(lp[(size_t)(t >> dlev) * CH + c]);
    partials[(size_t)(b * 64 + chunk) * 1024 + tid] = acc;
}

// grid (4, B), block 256: ctx[b*1024+d] = (sum over 64 chunks) / denom
__global__ __launch_bounds__(256) void ctx_reduce_kernel(
    const float* __restrict__ partials, const float* __restrict__ denomP,
    float* __restrict__ ctx)
{
    const int b = blockIdx.y;
    const int d = blockIdx.x * 256 + threadIdx.x;
    float acc = 0.0f;
    #pragma unroll
    for (int c = 0; c < 64; ++c) acc += partials[(size_t)(b * 64 + c) * 1024 + d];
    float den = 0.0f;
    #pragma unroll
    for (int c = 0; c < 64; ++c) den += denomP[b * 64 + c];
    ctx[b * 1024 + d] = acc / den;
}

// film[b,j] = ctx[b,:]·fw[j,:] + fb[j]. One wave per j, both batches.
__global__ __launch_bounds__(256) void film_kernel(
    const float* __restrict__ ctx, const float* __restrict__ fw,
    const float* __restrict__ fb, float* __restrict__ film)
{
    const int lane = threadIdx.x & 63;
    const int j = blockIdx.x * 4 + (threadIdx.x >> 6);  // 0..511
    float acc0 = 0.0f, acc1 = 0.0f;
    #pragma unroll
    for (int r = 0; r < 4; ++r) {
        float4 w4 = *((const float4*)(fw + (size_t)j * 1024 + r * 256) + lane);
        float4 c0 = *((const float4*)(ctx + r * 256) + lane);
        float4 c1 = *((const float4*)(ctx + 1024 + r * 256) + lane);
        acc0 += w4.x * c0.x + w4.y * c0.y + w4.z * c0.z + w4.w * c0.w;
        acc1 += w4.x * c1.x + w4.y * c1.y + w4.z * c1.z + w4.w * c1.w;
    }
    #pragma unroll
    for (int m = 1; m < 64; m <<= 1) {
        acc0 += __shfl_xor(acc0, m, 64);
        acc1 += __shfl_xor(acc1, m, 64);
    }
    if (lane == 0) {
        float b = fb[j];
        film[j] = acc0 + b;
        film[512 + j] = acc1 + b;
    }
}

// out = l16_0 * (1 + scale_f) + bias_f, 4 elem/thread (ushort4 -> float4)
__global__ void final_kernel(const unsigned short* __restrict__ lev0,
                             const float* __restrict__ film,
                             float* __restrict__ out)
{
    size_t n4 = ((size_t)blockIdx.x * 256 + threadIdx.x) * 4;
    int c = (int)(n4 & (CH - 1));
    int b = (int)(n4 >> 21);  // L*C = 2^21
    float4 h = ldb4_(lev0 + n4);
    const float* fs = film + b * 512;
    float4 o;
    o.x = h.x * (1.0f + fs[c + 0]) + fs[256 + c + 0];
    o.y = h.y * (1.0f + fs[c + 1]) + fs[256 + c + 1];
    o.z = h.z * (1.0f + fs[c + 2]) + fs[256 + c + 2];
    o.w = h.w * (1.0f + fs[c + 3]) + fs[256 + c + 3];
    *(float4*)(out + n4) = o;
}

extern "C" void kernel_launch(void* const* d_in, const int* in_sizes, int n_in,
                              void* d_out, int out_size, void* d_ws, size_t ws_size,
                              hipStream_t stream) {
    const float* x       = (const float*)d_in[0];
    const float* stem_w  = (const float*)d_in[1];
    const float* stem_b  = (const float*)d_in[2];
    const float* qkv_w   = (const float*)d_in[3];
    const float* width_w = (const float*)d_in[4];
    const float* width_b = (const float*)d_in[5];
    const float* out_w   = (const float*)d_in[6];
    const float* query   = (const float*)d_in[7];
    const float* film_w  = (const float*)d_in[8];
    const float* film_b  = (const float*)d_in[9];
    float* out = (float*)d_out;
    float* ws  = (float*)d_ws;

    // ---- workspace layout (fp32 region then bf16 region) ----
    float* partials = ws;                       // 131,072
    float* denomP   = partials + 131072;        // 128
    float* ctx      = denomP + 128;             // 2,048
    float* film     = ctx + 2048;               // 1,024
    unsigned short* x16g  = (unsigned short*)(film + 1024);  // 256 guard + 4,194,304
    unsigned short* h16_0 = x16g + 4194560;     // 4,194,304
    unsigned short* h16_1 = h16_0 + 4194304;    // 2,097,152
    unsigned short* h16_2 = h16_1 + 2097152;    // 1,048,576
    unsigned short* h16_3 = h16_2 + 1048576;    //   524,288
    unsigned short* qkv16 = h16_3 + 524288;     // 12,582,912
    unsigned short* ov16  = qkv16 + 12582912;   // 4,194,304 (reserved, unused)
    unsigned short* l16_0 = ov16 + 4194304;     // 4,194,304
    unsigned short* l16_1 = l16_0 + 4194304;    // 2,097,152
    unsigned short* l16_2 = l16_1 + 2097152;    // 1,048,576
    unsigned short* l16_3 = l16_2 + 1048576;    //   524,288
    unsigned short* qw16  = l16_3 + 524288;     //   196,608
    unsigned short* ow16  = qw16 + 196608;      //    65,536 (reserved, unused)
    unsigned short* sw16  = ow16 + 65536;       //   131,072
    unsigned short* h16[4]  = {h16_0, h16_1, h16_2, h16_3};
    unsigned short* l16[4]  = {l16_0, l16_1, l16_2, l16_3};
    (void)ov16; (void)ow16;

    // ---- fused prep (guard + x16 + q/k weights + stem) + Vp weight fold ----
    prep_kernel<<<NPREP_BLOCKS + 256, 256, 0, stream>>>(
        x, qkv_w, out_w, stem_w, x16g, qw16, sw16);

    // ---- stem conv as bf16 GEMM (A staged directly from x16) ----
    stem_gemm_bf16<<<dim3(CH / 128, B_SZ * L_SEQ / 128), 256, 0, stream>>>(
        x16g, sw16, h16_0, stem_b);

    // ---- hierarchy levels: qkv GEMM (q,k,Vp) + fused attn (K-split x2) ----
    for (int i = 0; i < NLEV; ++i) {
        const int l = L_SEQ >> i;
        const int M = B_SZ * l;
        gemm_bf16<<<dim3(768 / 128, M / 128), 256, 0, stream>>>(
            h16[i], qw16, qkv16, M, 768, CH);
        attn_vp_kernel<<<M / 64, 512, 0, stream>>>(
            qkv16, h16[i], width_w, width_b,
            l16[i], (i < NLEV - 1) ? h16[i + 1] : nullptr, l);
    }

    // ---- fused global-attention tail + FiLM ----
    tail_ctx_kernel<<<dim3(64, B_SZ), 1024, 0, stream>>>(
        l16_0, l16_1, l16_2, l16_3, query, partials, denomP);
    ctx_reduce_kernel<<<dim3(4, B_SZ), 256, 0, stream>>>(partials, denomP, ctx);
    film_kernel<<<128, 256, 0, stream>>>(ctx, film_w, film_b, film);
    final_kernel<<<(B_SZ * L_SEQ * CH) / 1024, 256, 0, stream>>>(l16_0, film, out);
}

// Round 7
// 226.993 us; speedup vs baseline: 1.3870x; 1.0630x over previous
//
#include <hip/hip_runtime.h>
#include <math.h>

#define L_SEQ 8192
#define B_SZ  2
#define CH    256
#define NLEV  4

typedef __attribute__((ext_vector_type(8))) short bf16x8;
typedef __attribute__((ext_vector_type(4))) float f32x4;

static __device__ __forceinline__ float sigmoidf_(float x) {
    return 1.0f / (1.0f + expf(-x));
}

// bf16 (stored as ushort) <-> fp32 helpers. bf2f is exact; f2b is RNE.
static __device__ __forceinline__ float bf2f_(unsigned short u) {
    union { unsigned int ui; float f; } x;
    x.ui = ((unsigned int)u) << 16;
    return x.f;
}
static __device__ __forceinline__ unsigned short f2b_(float f) {
    union { float f; unsigned int u; } x;
    x.f = f;
    unsigned int lsb = (x.u >> 16) & 1u;
    unsigned int r = x.u + 0x7fffu + lsb;
    return (unsigned short)(r >> 16);
}
static __device__ __forceinline__ float4 ldb4_(const unsigned short* p) {
    ushort4 u = *(const ushort4*)p;
    return make_float4(bf2f_(u.x), bf2f_(u.y), bf2f_(u.z), bf2f_(u.w));
}

// ---------------------------------------------------------------------------
// Fused fp32->bf16 prep + weight fold, one launch:
//   blocks [0, 17409):   guard row + x16 + qkv_w rows 0..511 + stem_w
//   blocks [17409, 17665): W'[c][j] = sum_k out_w[c][k]*qkv_w[512+k][j]
//     -> qw16 rows 512..767 (bf16).  Vp = v @ out_w^T, so attention's PV
//     output IS the level output: (P@V_win + v)@ow^T == P@Vp_win + Vp.
// ---------------------------------------------------------------------------
#define NPREP_BLOCKS 17409
__global__ __launch_bounds__(256) void prep_kernel(
    const float* __restrict__ x, const float* __restrict__ qkv_w,
    const float* __restrict__ out_w, const float* __restrict__ stem_w,
    unsigned short* __restrict__ x16g, unsigned short* __restrict__ qw16,
    unsigned short* __restrict__ sw16)
{
    __shared__ float owr[256];
    if (blockIdx.x >= NPREP_BLOCKS) {
        const int c = blockIdx.x - NPREP_BLOCKS, j = threadIdx.x;
        owr[j] = out_w[(size_t)c * 256 + j];
        __syncthreads();
        float acc = 0.0f;
        #pragma unroll 8
        for (int k = 0; k < 256; ++k)
            acc += owr[k] * qkv_w[(size_t)(512 + k) * 256 + j];
        qw16[(size_t)(512 + c) * 256 + j] = f2b_(acc);
        return;
    }
    int i = blockIdx.x * 256 + threadIdx.x;
    if (i < 256) { x16g[i] = 0; return; }           // guard row of zeros
    i -= 256;
    if (i < 4194304) { x16g[256 + i] = f2b_(x[i]); return; }
    i -= 4194304;
    if (i < 131072) { qw16[i] = f2b_(qkv_w[i]); return; }  // q,k rows only
    i -= 131072;
    {   // stem W: (256,512); k<256 -> tap0, else tap1
        int k = i & 511, nn = i >> 9;
        float v = (k < 256) ? stem_w[(size_t)nn * 512 + k * 2]
                            : stem_w[(size_t)nn * 512 + (k - 256) * 2 + 1];
        sw16[i] = f2b_(v);
    }
}

// ---------------------------------------------------------------------------
// Stem conv as MFMA GEMM, staging A directly from x16 (guard row at offset 0,
// row m data at x16g + (m+1)*256). Writes h16 (bias added).
// ---------------------------------------------------------------------------
__global__ __launch_bounds__(256) void stem_gemm_bf16(
    const unsigned short* __restrict__ x16g, const unsigned short* __restrict__ W,
    unsigned short* __restrict__ outB, const float* __restrict__ bias)
{
    __shared__ unsigned short As[128 * 32];
    __shared__ unsigned short Bs[128 * 32];
    const int tid  = threadIdx.x;
    const int wave = tid >> 6;
    const int lane = tid & 63;
    const int bm = blockIdx.y * 128;
    const int bn = blockIdx.x * 128;
    const int wm = (wave & 1) * 64;
    const int wn = (wave >> 1) * 64;
    const int srow = lane >> 2;
    const int scol = (lane & 3) * 8;

    f32x4 acc[4][4] = {};

    for (int k0 = 0; k0 < 512; k0 += 32) {
        __syncthreads();
        #pragma unroll
        for (int c = 0; c < 2; ++c) {
            const int chunk = c * 4 + wave;
            const int row = bm + chunk * 16 + srow;
            const int t = row & (L_SEQ - 1);
            const unsigned short* ga;
            if (k0 < 256)
                ga = x16g + (t > 0 ? (size_t)row * 256 : 0) + k0 + scol;
            else
                ga = x16g + ((size_t)row + 1) * 256 + (k0 - 256) + scol;
            const unsigned short* gw = W + (size_t)(bn + chunk * 16 + srow) * 512 + k0 + scol;
            __builtin_amdgcn_global_load_lds(
                (const __attribute__((address_space(1))) void*)ga,
                (__attribute__((address_space(3))) void*)(As + chunk * 16 * 32),
                16, 0, 0);
            __builtin_amdgcn_global_load_lds(
                (const __attribute__((address_space(1))) void*)gw,
                (__attribute__((address_space(3))) void*)(Bs + chunk * 16 * 32),
                16, 0, 0);
        }
        __syncthreads();

        bf16x8 af[4], bf[4];
        const int fr = lane & 15;
        const int kk = (lane >> 4) * 8;
        #pragma unroll
        for (int i = 0; i < 4; ++i) {
            af[i] = *(const bf16x8*)(As + (wm + i * 16 + fr) * 32 + kk);
            bf[i] = *(const bf16x8*)(Bs + (wn + i * 16 + fr) * 32 + kk);
        }
        #pragma unroll
        for (int i = 0; i < 4; ++i)
            #pragma unroll
            for (int j = 0; j < 4; ++j)
                acc[i][j] = __builtin_amdgcn_mfma_f32_16x16x32_bf16(
                    af[i], bf[j], acc[i][j], 0, 0, 0);
    }

    const int cn = lane & 15;
    const int cr = (lane >> 4) * 4;
    #pragma unroll
    for (int i = 0; i < 4; ++i)
        #pragma unroll
        for (int r = 0; r < 4; ++r) {
            const int m = bm + wm + i * 16 + cr + r;
            #pragma unroll
            for (int j = 0; j < 4; ++j) {
                const int n = bn + wn + j * 16 + cn;
                outB[(size_t)m * CH + n] = f2b_(acc[i][j][r] + bias[n]);
            }
        }
}

// ---------------------------------------------------------------------------
// FULLY fused level kernel: qkv projection + width head + QK^T (K-split x2)
// + softmax (+Vp residual via P-center +1) + Vp projection + PV + downsample.
// 512 threads = 8 waves per 64-row block; halo = 80 rows.
//
// LDS plan (127,232 B -> 1 block/CU, 2 waves/SIMD):
//   hs [80][256]  @0       : H halo, swizzled via PRE-SWIZZLED global source
//                            (global_load_lds writes linearly; rule #21)
//   qs [64][256]  @40960   : q (bf16, XOR-swizzled), written by MFMA C-layout
//   ks [80][256]  @73728   : k (bf16, XOR-swizzled)
//   vt [256][88]  @40960   : Vp^T — ALIASES qs/ks after QK^T is done
//   pb 4x[16][32] @114688  : P per row tile
//   sp1           @118784  : half-1 partial S (fp32)
//   ws1           @126976  : half-1 width partials
//
// Numerics: identical MFMA shape + ascending k-chunk chain + f2b_ rounding
// points as the previous standalone gemm_bf16 + attn pair; zeroed OOR halo
// rows reproduce the reference zero-padding -> bitwise-identical output.
// ---------------------------------------------------------------------------
__global__ __launch_bounds__(512, 2) void level_fused_kernel(
    const unsigned short* __restrict__ h16in, const unsigned short* __restrict__ qw,
    const unsigned short* __restrict__ zrow,
    const float* __restrict__ ww, const float* __restrict__ wbp,
    unsigned short* __restrict__ l16o, unsigned short* __restrict__ dsB, int l)
{
    __shared__ __align__(16) char smem[127232];
    unsigned short* hs = (unsigned short*)smem;              // 40960 B
    unsigned short* qs = (unsigned short*)(smem + 40960);    // 32768 B
    unsigned short* ks = (unsigned short*)(smem + 73728);    // 40960 B
    unsigned short* vt = (unsigned short*)(smem + 40960);    // 45056 B (alias)
    unsigned short* pb = (unsigned short*)(smem + 114688);   //  4096 B
    float* sp1 = (float*)(smem + 118784);                    //  8192 B
    float* ws1 = (float*)(smem + 126976);                    //   256 B

    const int tid  = threadIdx.x;
    const int wave = tid >> 6;
    const int lane = tid & 63;
    const int rt   = wave & 3;    // row tile 0..3
    const int half = wave >> 2;   // channel half 0..1 (QK/PV phases)
    const int q    = lane >> 4;
    const int n    = lane & 15;

    // XCD-aware swizzle (grid is always a multiple of 8)
    int bid = blockIdx.x;
    const int cpx = gridDim.x >> 3;
    bid = (bid & 7) * cpx + (bid >> 3);

    const int bps = l >> 6;
    const int b  = bid / bps;
    const int t0 = (bid % bps) << 6;
    const size_t seqbase = (size_t)b * l;
    const int row0 = t0 + rt * 16;

    // ======== stage H halo (80 rows x 256 ch); source pre-swizzled ========
    #pragma unroll
    for (int i = 0; i < 5; ++i) {
        const int task = i * 512 + tid;
        const int r = task >> 5, ch = task & 31;
        const int grow = t0 - 8 + r;
        const unsigned short* src = (grow >= 0 && grow < l)
            ? h16in + (seqbase + grow) * 256 + ((ch ^ (r & 7)) << 3)
            : zrow;                               // 512 B of zeros
        __builtin_amdgcn_global_load_lds(
            (const __attribute__((address_space(1))) void*)src,
            (__attribute__((address_space(3))) void*)
                (hs + (size_t)(i * 512 + (tid & ~63)) * 8),
            16, 0, 0);
    }
    __syncthreads();

    // ======== phase A: project q,k — wave owns col-tiles {2w, 2w+1} ========
    const int ct0 = wave * 2;
    {   // ---- q (weight rows 0..255) -> qs rows 0..63 ----
        bf16x8 bwa[8], bwb[8];
        const unsigned short* wa_ = qw + (size_t)(ct0 * 16 + n) * 256 + q * 8;
        const unsigned short* wb_ = qw + (size_t)((ct0 + 1) * 16 + n) * 256 + q * 8;
        #pragma unroll
        for (int j = 0; j < 8; ++j) {
            bwa[j] = *(const bf16x8*)(wa_ + j * 32);
            bwb[j] = *(const bf16x8*)(wb_ + j * 32);
        }
        #pragma unroll
        for (int rtq = 0; rtq < 4; ++rtq) {
            const int hr = 8 + rtq * 16 + n;
            const int hswz = (hr & 7) << 4;
            bf16x8 af[8];
            #pragma unroll
            for (int j = 0; j < 8; ++j)
                af[j] = *(const bf16x8*)((const char*)hs +
                         ((hr * 512 + (j * 32 + q * 8) * 2) ^ hswz));
            f32x4 aA = {}, aB = {};
            #pragma unroll
            for (int j = 0; j < 8; ++j) {
                aA = __builtin_amdgcn_mfma_f32_16x16x32_bf16(af[j], bwa[j], aA, 0, 0, 0);
                aB = __builtin_amdgcn_mfma_f32_16x16x32_bf16(af[j], bwb[j], aB, 0, 0, 0);
            }
            #pragma unroll
            for (int idx = 0; idx < 4; ++idx) {
                const int row = rtq * 16 + q * 4 + idx;
                const int rswz = (row & 7) << 4;
                *(unsigned short*)((char*)qs +
                    ((row * 512 + (ct0 * 16 + n) * 2) ^ rswz)) = f2b_(aA[idx]);
                *(unsigned short*)((char*)qs +
                    ((row * 512 + ((ct0 + 1) * 16 + n) * 2) ^ rswz)) = f2b_(aB[idx]);
            }
        }
    }
    {   // ---- k (weight rows 256..511) -> ks halo rows 0..79 ----
        bf16x8 bwa[8], bwb[8];
        const unsigned short* wa_ = qw + (size_t)(256 + ct0 * 16 + n) * 256 + q * 8;
        const unsigned short* wb_ = qw + (size_t)(256 + (ct0 + 1) * 16 + n) * 256 + q * 8;
        #pragma unroll
        for (int j = 0; j < 8; ++j) {
            bwa[j] = *(const bf16x8*)(wa_ + j * 32);
            bwb[j] = *(const bf16x8*)(wb_ + j * 32);
        }
        #pragma unroll
        for (int rtk = 0; rtk < 5; ++rtk) {
            const int hr = rtk * 16 + n;
            const int hswz = (hr & 7) << 4;
            bf16x8 af[8];
            #pragma unroll
            for (int j = 0; j < 8; ++j)
                af[j] = *(const bf16x8*)((const char*)hs +
                         ((hr * 512 + (j * 32 + q * 8) * 2) ^ hswz));
            f32x4 aA = {}, aB = {};
            #pragma unroll
            for (int j = 0; j < 8; ++j) {
                aA = __builtin_amdgcn_mfma_f32_16x16x32_bf16(af[j], bwa[j], aA, 0, 0, 0);
                aB = __builtin_amdgcn_mfma_f32_16x16x32_bf16(af[j], bwb[j], aB, 0, 0, 0);
            }
            #pragma unroll
            for (int idx = 0; idx < 4; ++idx) {
                const int row = rtk * 16 + q * 4 + idx;
                const int rswz = (row & 7) << 4;
                *(unsigned short*)((char*)ks +
                    ((row * 512 + (ct0 * 16 + n) * 2) ^ rswz)) = f2b_(aA[idx]);
                *(unsigned short*)((char*)ks +
                    ((row * 512 + ((ct0 + 1) * 16 + n) * 2) ^ rswz)) = f2b_(aB[idx]);
            }
        }
    }
    __syncthreads();   // qs/ks fully written

    // ======== width head partial (32 channels per lane, from hs) ========
    const int kc0 = half * 128;
    float wdot = 0.0f;
    {
        const int hr = 8 + rt * 16 + n;
        const int hswz = (hr & 7) << 4;
        #pragma unroll
        for (int jj = 0; jj < 4; ++jj) {
            bf16x8 hv = *(const bf16x8*)((const char*)hs +
                        ((hr * 512 + (kc0 + q * 32 + jj * 8) * 2) ^ hswz));
            float4 wa = *((const float4*)(ww + kc0 + q * 32 + jj * 8));
            float4 wc = *((const float4*)(ww + kc0 + q * 32 + jj * 8 + 4));
            wdot += bf2f_((unsigned short)hv[0]) * wa.x
                  + bf2f_((unsigned short)hv[1]) * wa.y
                  + bf2f_((unsigned short)hv[2]) * wa.z
                  + bf2f_((unsigned short)hv[3]) * wa.w
                  + bf2f_((unsigned short)hv[4]) * wc.x
                  + bf2f_((unsigned short)hv[5]) * wc.y
                  + bf2f_((unsigned short)hv[6]) * wc.z
                  + bf2f_((unsigned short)hv[7]) * wc.w;
        }
    }
    wdot += __shfl_xor(wdot, 16, 64);
    wdot += __shfl_xor(wdot, 32, 64);
    if (half == 1 && q == 0) ws1[rt * 16 + n] = wdot;

    // ======== QK^T partial from LDS (4 k-chunks of this half) ========
    f32x4 accS[2] = {};
    {
        const int qrow = rt * 16 + n;
        const int qswz = (qrow & 7) << 4;
        bf16x8 qf[4];
        #pragma unroll
        for (int j = 0; j < 4; ++j)
            qf[j] = *(const bf16x8*)((const char*)qs +
                     ((qrow * 512 + (kc0 + q * 8 + j * 32) * 2) ^ qswz));
        #pragma unroll
        for (int h = 0; h < 2; ++h) {
            const int rk = rt * 16 + h * 16 + n;
            const int kswz = (rk & 7) << 4;
            #pragma unroll
            for (int j = 0; j < 4; ++j) {
                bf16x8 kb = *(const bf16x8*)((const char*)ks +
                            ((rk * 512 + (kc0 + q * 8 + j * 32) * 2) ^ kswz));
                accS[h] = __builtin_amdgcn_mfma_f32_16x16x32_bf16(
                    qf[j], kb, accS[h], 0, 0, 0);
            }
        }
    }
    if (half == 1) {
        *(f32x4*)(sp1 + ((rt * 2 + 0) * 64 + lane) * 4) = accS[0];
        *(f32x4*)(sp1 + ((rt * 2 + 1) * 64 + lane) * 4) = accS[1];
    }
    __syncthreads();   // sp1 + ws1 staged; qs/ks reads complete

    if (half == 0) {
        accS[0] += *(const f32x4*)(sp1 + ((rt * 2 + 0) * 64 + lane) * 4);
        accS[1] += *(const f32x4*)(sp1 + ((rt * 2 + 1) * 64 + lane) * 4);
        const float w_n = sigmoidf_(wdot + ws1[rt * 16 + n] + wbp[0]) * 8.0f + 0.5f;

        float wd[4];
        #pragma unroll
        for (int r = 0; r < 4; ++r) wd[r] = __shfl(w_n, q * 4 + r, 64);

        float s[2][4];
        #pragma unroll
        for (int h = 0; h < 2; ++h)
            #pragma unroll
            for (int r = 0; r < 4; ++r) {
                int ii = q * 4 + r;
                int c  = h * 16 + n;
                int w  = c - ii;
                float dist = fabsf((float)w - 8.0f);
                float sm = sigmoidf_((wd[r] - dist) * 5.0f);
                float v = accS[h][r] * 0.0625f - (1.0f - sm) * 10000.0f;
                s[h][r] = (w >= 0 && w <= 16) ? v : -3.0e38f;
            }

        float mx[4], sum[4];
        #pragma unroll
        for (int r = 0; r < 4; ++r) mx[r] = fmaxf(s[0][r], s[1][r]);
        #pragma unroll
        for (int m = 1; m < 16; m <<= 1)
            #pragma unroll
            for (int r = 0; r < 4; ++r) mx[r] = fmaxf(mx[r], __shfl_xor(mx[r], m, 64));
        float e[2][4];
        #pragma unroll
        for (int h = 0; h < 2; ++h)
            #pragma unroll
            for (int r = 0; r < 4; ++r) e[h][r] = expf(s[h][r] - mx[r]);
        #pragma unroll
        for (int r = 0; r < 4; ++r) sum[r] = e[0][r] + e[1][r];
        #pragma unroll
        for (int m = 1; m < 16; m <<= 1)
            #pragma unroll
            for (int r = 0; r < 4; ++r) sum[r] += __shfl_xor(sum[r], m, 64);

        // write P (bf16), folding the +Vp[t] residual: +1 at center c == ii+8
        #pragma unroll
        for (int h = 0; h < 2; ++h)
            #pragma unroll
            for (int r = 0; r < 4; ++r) {
                int ii = q * 4 + r, c = h * 16 + n;
                float p = e[h][r] / sum[r];
                if (c == ii + 8) p += 1.0f;
                pb[rt * 512 + ii * 32 + c] = f2b_(p);
            }
    }
    __syncthreads();   // pb ready; qs/ks now dead -> vt may overwrite

    // ======== phase B: project Vp (weight rows 512..767) into vt ========
    {
        bf16x8 bwa[8], bwb[8];
        const unsigned short* wa_ = qw + (size_t)(512 + ct0 * 16 + n) * 256 + q * 8;
        const unsigned short* wb_ = qw + (size_t)(512 + (ct0 + 1) * 16 + n) * 256 + q * 8;
        #pragma unroll
        for (int j = 0; j < 8; ++j) {
            bwa[j] = *(const bf16x8*)(wa_ + j * 32);
            bwb[j] = *(const bf16x8*)(wb_ + j * 32);
        }
        #pragma unroll
        for (int rtv = 0; rtv < 5; ++rtv) {
            const int hr = rtv * 16 + n;
            const int hswz = (hr & 7) << 4;
            bf16x8 af[8];
            #pragma unroll
            for (int j = 0; j < 8; ++j)
                af[j] = *(const bf16x8*)((const char*)hs +
                         ((hr * 512 + (j * 32 + q * 8) * 2) ^ hswz));
            f32x4 aA = {}, aB = {};
            #pragma unroll
            for (int j = 0; j < 8; ++j) {
                aA = __builtin_amdgcn_mfma_f32_16x16x32_bf16(af[j], bwa[j], aA, 0, 0, 0);
                aB = __builtin_amdgcn_mfma_f32_16x16x32_bf16(af[j], bwb[j], aB, 0, 0, 0);
            }
            // Vt[c][r]: 4 consecutive r per lane -> one 8 B store per ct
            ushort4 pA, pB;
            pA.x = f2b_(aA[0]); pA.y = f2b_(aA[1]); pA.z = f2b_(aA[2]); pA.w = f2b_(aA[3]);
            pB.x = f2b_(aB[0]); pB.y = f2b_(aB[1]); pB.z = f2b_(aB[2]); pB.w = f2b_(aB[3]);
            const int rb = rtv * 16 + q * 4;
            *(ushort4*)(vt + (size_t)(ct0 * 16 + n) * 88 + rb) = pA;
            *(ushort4*)(vt + (size_t)((ct0 + 1) * 16 + n) * 88 + rb) = pB;
        }
    }
    __syncthreads();   // vt ready

    // ======== PV: this wave handles ct = half*8 .. half*8+7 ========
    bf16x8 pf = *(const bf16x8*)(pb + rt * 512 + n * 32 + q * 8);
    const int rl = q * 4;                       // even
    const size_t gbase = seqbase + row0;
    #pragma unroll
    for (int c = 0; c < 8; ++c) {
        const int ct = half * 8 + c;
        bf16x8 vf = *(const bf16x8*)(vt + (ct * 16 + n) * 88 + rt * 16 + q * 8);
        f32x4 z = {};
        f32x4 o = __builtin_amdgcn_mfma_f32_16x16x32_bf16(pf, vf, z, 0, 0, 0);
        const int col = ct * 16 + n;
        float v0 = o[0], v1 = o[1], v2 = o[2], v3 = o[3];
        size_t r0 = (gbase + rl) * CH + col;
        l16o[r0]          = f2b_(v0);
        l16o[r0 + CH]     = f2b_(v1);
        l16o[r0 + 2 * CH] = f2b_(v2);
        l16o[r0 + 3 * CH] = f2b_(v3);
        if (dsB) {
            size_t d0 = ((gbase + rl) >> 1) * CH + col;
            dsB[d0]      = f2b_(0.5f * (v0 + v1));
            dsB[d0 + CH] = f2b_(0.5f * (v2 + v3));
        }
    }
}

// ---------------------------------------------------------------------------
// Fused global-attention tail: per block (chunk of 128 t's, batch b):
//   pass 1: e[t] = exp(concat[t]·query)  (unnormalized softmax — |s| small)
//   pass 2: partials[d] = sum_t e[t]*concat[t][d]; denomP = sum_t e[t]
// grid (64, B), block 1024.
// ---------------------------------------------------------------------------
__global__ __launch_bounds__(1024) void tail_ctx_kernel(
    const unsigned short* __restrict__ l0, const unsigned short* __restrict__ l1,
    const unsigned short* __restrict__ l2, const unsigned short* __restrict__ l3,
    const float* __restrict__ query, float* __restrict__ partials,
    float* __restrict__ denomP)
{
    __shared__ float eS[128];
    const int tid = threadIdx.x;
    const int chunk = blockIdx.x, b = blockIdx.y;
    const int t0 = chunk * 128;
    const unsigned short* levp[4] = {l0, l1, l2, l3};

    // ---- pass 1: wave w computes e for t = t0 + w*8 + j ----
    const int w = tid >> 6, lane = tid & 63;
    const int lev = lane >> 4, c0 = (lane & 15) * 16;
    const unsigned short* lpbase = levp[lev] + (size_t)b * (L_SEQ >> lev) * CH;
    const float* qp = query + lev * CH + c0;
    float4 q0 = *(const float4*)(qp);
    float4 q1 = *(const float4*)(qp + 4);
    float4 q2 = *(const float4*)(qp + 8);
    float4 q3 = *(const float4*)(qp + 12);
    #pragma unroll
    for (int j = 0; j < 8; ++j) {
        int t = t0 + w * 8 + j;
        const unsigned short* p = lpbase + (size_t)(t >> lev) * CH + c0;
        float4 h0 = ldb4_(p), h1 = ldb4_(p + 4), h2 = ldb4_(p + 8), h3 = ldb4_(p + 12);
        float part = h0.x * q0.x + h0.y * q0.y + h0.z * q0.z + h0.w * q0.w
                   + h1.x * q1.x + h1.y * q1.y + h1.z * q1.z + h1.w * q1.w
                   + h2.x * q2.x + h2.y * q2.y + h2.z * q2.z + h2.w * q2.w
                   + h3.x * q3.x + h3.y * q3.y + h3.z * q3.z + h3.w * q3.w;
        #pragma unroll
        for (int m = 1; m < 64; m <<= 1) part += __shfl_xor(part, m, 64);
        if (lane == 0) eS[w * 8 + j] = expf(part);
    }
    __syncthreads();

    if (tid == 0) {
        float ds = 0.0f;
        #pragma unroll 8
        for (int i = 0; i < 128; ++i) ds += eS[i];
        denomP[b * 64 + chunk] = ds;
    }

    // ---- pass 2: weighted accumulation (rows are L2-hot from pass 1) ----
    const int dlev = tid >> 8, c = tid & 255;
    const unsigned short* lp = levp[dlev] + (size_t)b * (L_SEQ >> dlev) * CH;
    float acc = 0.0f;
    #pragma unroll 4
    for (int t = t0; t < t0 + 128; ++t)
        acc += eS[t - t0] * bf2f_(lp[(size_t)(t >> dlev) * CH + c]);
    partials[(size_t)(b * 64 + chunk) * 1024 + tid] = acc;
}

// grid (4, B), block 256: ctx[b*1024+d] = (sum over 64 chunks) / denom
__global__ __launch_bounds__(256) void ctx_reduce_kernel(
    const float* __restrict__ partials, const float* __restrict__ denomP,
    float* __restrict__ ctx)
{
    const int b = blockIdx.y;
    const int d = blockIdx.x * 256 + threadIdx.x;
    float acc = 0.0f;
    #pragma unroll
    for (int c = 0; c < 64; ++c) acc += partials[(size_t)(b * 64 + c) * 1024 + d];
    float den = 0.0f;
    #pragma unroll
    for (int c = 0; c < 64; ++c) den += denomP[b * 64 + c];
    ctx[b * 1024 + d] = acc / den;
}

// film[b,j] = ctx[b,:]·fw[j,:] + fb[j]. One wave per j, both batches.
__global__ __launch_bounds__(256) void film_kernel(
    const float* __restrict__ ctx, const float* __restrict__ fw,
    const float* __restrict__ fb, float* __restrict__ film)
{
    const int lane = threadIdx.x & 63;
    const int j = blockIdx.x * 4 + (threadIdx.x >> 6);  // 0..511
    float acc0 = 0.0f, acc1 = 0.0f;
    #pragma unroll
    for (int r = 0; r < 4; ++r) {
        float4 w4 = *((const float4*)(fw + (size_t)j * 1024 + r * 256) + lane);
        float4 c0 = *((const float4*)(ctx + r * 256) + lane);
        float4 c1 = *((const float4*)(ctx + 1024 + r * 256) + lane);
        acc0 += w4.x * c0.x + w4.y * c0.y + w4.z * c0.z + w4.w * c0.w;
        acc1 += w4.x * c1.x + w4.y * c1.y + w4.z * c1.z + w4.w * c1.w;
    }
    #pragma unroll
    for (int m = 1; m < 64; m <<= 1) {
        acc0 += __shfl_xor(acc0, m, 64);
        acc1 += __shfl_xor(acc1, m, 64);
    }
    if (lane == 0) {
        float b = fb[j];
        film[j] = acc0 + b;
        film[512 + j] = acc1 + b;
    }
}

// out = l16_0 * (1 + scale_f) + bias_f, 4 elem/thread (ushort4 -> float4)
__global__ void final_kernel(const unsigned short* __restrict__ lev0,
                             const float* __restrict__ film,
                             float* __restrict__ out)
{
    size_t n4 = ((size_t)blockIdx.x * 256 + threadIdx.x) * 4;
    int c = (int)(n4 & (CH - 1));
    int b = (int)(n4 >> 21);  // L*C = 2^21
    float4 h = ldb4_(lev0 + n4);
    const float* fs = film + b * 512;
    float4 o;
    o.x = h.x * (1.0f + fs[c + 0]) + fs[256 + c + 0];
    o.y = h.y * (1.0f + fs[c + 1]) + fs[256 + c + 1];
    o.z = h.z * (1.0f + fs[c + 2]) + fs[256 + c + 2];
    o.w = h.w * (1.0f + fs[c + 3]) + fs[256 + c + 3];
    *(float4*)(out + n4) = o;
}

extern "C" void kernel_launch(void* const* d_in, const int* in_sizes, int n_in,
                              void* d_out, int out_size, void* d_ws, size_t ws_size,
                              hipStream_t stream) {
    const float* x       = (const float*)d_in[0];
    const float* stem_w  = (const float*)d_in[1];
    const float* stem_b  = (const float*)d_in[2];
    const float* qkv_w   = (const float*)d_in[3];
    const float* width_w = (const float*)d_in[4];
    const float* width_b = (const float*)d_in[5];
    const float* out_w   = (const float*)d_in[6];
    const float* query   = (const float*)d_in[7];
    const float* film_w  = (const float*)d_in[8];
    const float* film_b  = (const float*)d_in[9];
    float* out = (float*)d_out;
    float* ws  = (float*)d_ws;

    // ---- workspace layout (fp32 region then bf16 region) ----
    float* partials = ws;                       // 131,072
    float* denomP   = partials + 131072;        // 128
    float* ctx      = denomP + 128;             // 2,048
    float* film     = ctx + 2048;               // 1,024
    unsigned short* x16g  = (unsigned short*)(film + 1024);  // 256 guard + 4,194,304
    unsigned short* h16_0 = x16g + 4194560;     // 4,194,304
    unsigned short* h16_1 = h16_0 + 4194304;    // 2,097,152
    unsigned short* h16_2 = h16_1 + 2097152;    // 1,048,576
    unsigned short* h16_3 = h16_2 + 1048576;    //   524,288
    unsigned short* qkv16 = h16_3 + 524288;     // 12,582,912 (reserved, unused)
    unsigned short* ov16  = qkv16 + 12582912;   // 4,194,304 (reserved, unused)
    unsigned short* l16_0 = ov16 + 4194304;     // 4,194,304
    unsigned short* l16_1 = l16_0 + 4194304;    // 2,097,152
    unsigned short* l16_2 = l16_1 + 2097152;    // 1,048,576
    unsigned short* l16_3 = l16_2 + 1048576;    //   524,288
    unsigned short* qw16  = l16_3 + 524288;     //   196,608
    unsigned short* ow16  = qw16 + 196608;      //    65,536 (reserved, unused)
    unsigned short* sw16  = ow16 + 65536;       //   131,072
    unsigned short* h16[4]  = {h16_0, h16_1, h16_2, h16_3};
    unsigned short* l16[4]  = {l16_0, l16_1, l16_2, l16_3};
    (void)qkv16; (void)ov16; (void)ow16;

    // ---- fused prep (guard + x16 + q/k weights + stem) + Vp weight fold ----
    prep_kernel<<<NPREP_BLOCKS + 256, 256, 0, stream>>>(
        x, qkv_w, out_w, stem_w, x16g, qw16, sw16);

    // ---- stem conv as bf16 GEMM (A staged directly from x16) ----
    stem_gemm_bf16<<<dim3(CH / 128, B_SZ * L_SEQ / 128), 256, 0, stream>>>(
        x16g, sw16, h16_0, stem_b);

    // ---- hierarchy levels: ONE fused kernel per level (proj + attn + ds) ---
    for (int i = 0; i < NLEV; ++i) {
        const int l = L_SEQ >> i;
        const int M = B_SZ * l;
        level_fused_kernel<<<M / 64, 512, 0, stream>>>(
            h16[i], qw16, x16g /* 512 B zero row */, width_w, width_b,
            l16[i], (i < NLEV - 1) ? h16[i + 1] : nullptr, l);
    }

    // ---- fused global-attention tail + FiLM ----
    tail_ctx_kernel<<<dim3(64, B_SZ), 1024, 0, stream>>>(
        l16_0, l16_1, l16_2, l16_3, query, partials, denomP);
    ctx_reduce_kernel<<<dim3(4, B_SZ), 256, 0, stream>>>(partials, denomP, ctx);
    film_kernel<<<128, 256, 0, stream>>>(ctx, film_w, film_b, film);
    final_kernel<<<(B_SZ * L_SEQ * CH) / 1024, 256, 0, stream>>>(l16_0, film, out);
}

// Round 8
// 225.508 us; speedup vs baseline: 1.3962x; 1.0066x over previous
//
#include <hip/hip_runtime.h>
#include <math.h>

#define L_SEQ 8192
#define B_SZ  2
#define CH    256
#define NLEV  4

typedef __attribute__((ext_vector_type(8))) short bf16x8;
typedef __attribute__((ext_vector_type(4))) float f32x4;

static __device__ __forceinline__ float sigmoidf_(float x) {
    return 1.0f / (1.0f + expf(-x));
}

// bf16 (stored as ushort) <-> fp32 helpers. bf2f is exact; f2b is RNE.
static __device__ __forceinline__ float bf2f_(unsigned short u) {
    union { unsigned int ui; float f; } x;
    x.ui = ((unsigned int)u) << 16;
    return x.f;
}
static __device__ __forceinline__ unsigned short f2b_(float f) {
    union { float f; unsigned int u; } x;
    x.f = f;
    unsigned int lsb = (x.u >> 16) & 1u;
    unsigned int r = x.u + 0x7fffu + lsb;
    return (unsigned short)(r >> 16);
}
static __device__ __forceinline__ float4 ldb4_(const unsigned short* p) {
    ushort4 u = *(const ushort4*)p;
    return make_float4(bf2f_(u.x), bf2f_(u.y), bf2f_(u.z), bf2f_(u.w));
}

// ---------------------------------------------------------------------------
// Fused fp32->bf16 prep + weight fold, one launch:
//   blocks [0, 17409):   guard row + x16 + qkv_w rows 0..511 + stem_w
//   blocks [17409, 17665): W'[c][j] = sum_k out_w[c][k]*qkv_w[512+k][j]
//     -> qw16 rows 512..767 (bf16).  Vp = v @ out_w^T, so attention's PV
//     output IS the level output: (P@V_win + v)@ow^T == P@Vp_win + Vp.
// ---------------------------------------------------------------------------
#define NPREP_BLOCKS 17409
__global__ __launch_bounds__(256) void prep_kernel(
    const float* __restrict__ x, const float* __restrict__ qkv_w,
    const float* __restrict__ out_w, const float* __restrict__ stem_w,
    unsigned short* __restrict__ x16g, unsigned short* __restrict__ qw16,
    unsigned short* __restrict__ sw16)
{
    __shared__ float owr[256];
    if (blockIdx.x >= NPREP_BLOCKS) {
        const int c = blockIdx.x - NPREP_BLOCKS, j = threadIdx.x;
        owr[j] = out_w[(size_t)c * 256 + j];
        __syncthreads();
        float acc = 0.0f;
        #pragma unroll 8
        for (int k = 0; k < 256; ++k)
            acc += owr[k] * qkv_w[(size_t)(512 + k) * 256 + j];
        qw16[(size_t)(512 + c) * 256 + j] = f2b_(acc);
        return;
    }
    int i = blockIdx.x * 256 + threadIdx.x;
    if (i < 256) { x16g[i] = 0; return; }           // guard row of zeros
    i -= 256;
    if (i < 4194304) { x16g[256 + i] = f2b_(x[i]); return; }
    i -= 4194304;
    if (i < 131072) { qw16[i] = f2b_(qkv_w[i]); return; }  // q,k rows only
    i -= 131072;
    {   // stem W: (256,512); k<256 -> tap0, else tap1
        int k = i & 511, nn = i >> 9;
        float v = (k < 256) ? stem_w[(size_t)nn * 512 + k * 2]
                            : stem_w[(size_t)nn * 512 + (k - 256) * 2 + 1];
        sw16[i] = f2b_(v);
    }
}

// ---------------------------------------------------------------------------
// FULLY fused level kernel.  STEM=1 (level 0): additionally computes the
// stem conv h = conv(x)+bias IN-BLOCK (bitwise-identical MFMA chain to the
// old standalone stem GEMM) instead of staging h16 from global — removes
// the h16_0 HBM round trip and one launch.  STEM=0: stages H halo from
// global (levels 1..3).
//
// 512 threads = 8 waves per 64-row block; halo = 80 rows.
// LDS plan (127,232 B -> 1 block/CU, 2 waves/SIMD):
//   hs [80][256]  @0       : H halo (swizzled)
//   xs [81][256]  @40960   : x halo for stem (STEM=1; aliases qs/ks, dead
//                            before qs/ks are written)
//   qs [64][256]  @40960   : q (bf16, XOR-swizzled)
//   ks [80][256]  @73728   : k (bf16, XOR-swizzled)
//   vt [256][88]  @40960   : Vp^T — aliases qs/ks after QK^T is done
//   pb 4x[16][32] @114688  : P per row tile
//   sp1           @118784  : half-1 partial S (fp32)
//   ws1           @126976  : half-1 width partials
// ---------------------------------------------------------------------------
template<int STEM>
__global__ __launch_bounds__(512, 2) void level_fused_kernel(
    const unsigned short* __restrict__ h16in, const unsigned short* __restrict__ x16g,
    const unsigned short* __restrict__ sw, const float* __restrict__ sbias,
    const unsigned short* __restrict__ qw,
    const float* __restrict__ ww, const float* __restrict__ wbp,
    unsigned short* __restrict__ l16o, unsigned short* __restrict__ dsB, int l)
{
    __shared__ __align__(16) char smem[127232];
    unsigned short* hs = (unsigned short*)smem;              // 40960 B
    unsigned short* xs = (unsigned short*)(smem + 40960);    // 41472 B (alias)
    unsigned short* qs = (unsigned short*)(smem + 40960);    // 32768 B
    unsigned short* ks = (unsigned short*)(smem + 73728);    // 40960 B
    unsigned short* vt = (unsigned short*)(smem + 40960);    // 45056 B (alias)
    unsigned short* pb = (unsigned short*)(smem + 114688);   //  4096 B
    float* sp1 = (float*)(smem + 118784);                    //  8192 B
    float* ws1 = (float*)(smem + 126976);                    //   256 B

    const int tid  = threadIdx.x;
    const int wave = tid >> 6;
    const int lane = tid & 63;
    const int rt   = wave & 3;    // row tile 0..3
    const int half = wave >> 2;   // channel half 0..1 (QK/PV phases)
    const int q    = lane >> 4;
    const int n    = lane & 15;

    // XCD-aware swizzle (grid is always a multiple of 8)
    int bid = blockIdx.x;
    const int cpx = gridDim.x >> 3;
    bid = (bid & 7) * cpx + (bid >> 3);

    const int bps = l >> 6;
    const int b  = bid / bps;
    const int t0 = (bid % bps) << 6;
    const size_t seqbase = (size_t)b * l;
    const int row0 = t0 + rt * 16;
    const int ct0 = wave * 2;

    if constexpr (STEM) {
        // ---- stage x halo: 81 rows (gx = t0-9 .. t0+71), pre-swizzled src --
        #pragma unroll
        for (int i = 0; i < 6; ++i) {
            const int task = i * 512 + tid;
            if (task < 2592) {
                const int r = task >> 5, ch = task & 31;
                const int gx = t0 - 9 + r;
                const unsigned short* src = (gx >= 0 && gx < l)
                    ? x16g + ((size_t)(seqbase + gx) + 1) * 256 + ((ch ^ (r & 7)) << 3)
                    : x16g;                       // guard zeros
                __builtin_amdgcn_global_load_lds(
                    (const __attribute__((address_space(1))) void*)src,
                    (__attribute__((address_space(3))) void*)
                        (xs + (size_t)(i * 512 + (tid & ~63)) * 8),
                    16, 0, 0);
            }
        }
        __syncthreads();

        // ---- in-block stem GEMM: h rows 0..79, wave owns out-ch {ct0,ct0+1}
        // Chain: k chunks 0..15 ascending (pass0 = tap0 rows, pass1 = tap1),
        // identical to the old standalone stem GEMM -> bitwise-identical h.
        f32x4 accA[5] = {}, accB[5] = {};
        #pragma unroll
        for (int pass = 0; pass < 2; ++pass) {
            bf16x8 wA[8], wB[8];
            const unsigned short* wa_ = sw + (size_t)(ct0 * 16 + n) * 512 + pass * 256 + q * 8;
            const unsigned short* wb_ = sw + (size_t)((ct0 + 1) * 16 + n) * 512 + pass * 256 + q * 8;
            #pragma unroll
            for (int j = 0; j < 8; ++j) {
                wA[j] = *(const bf16x8*)(wa_ + j * 32);
                wB[j] = *(const bf16x8*)(wb_ + j * 32);
            }
            #pragma unroll
            for (int rtile = 0; rtile < 5; ++rtile) {
                const int xr = rtile * 16 + n + pass;   // tap0: row hr, tap1: hr+1
                const int xswz = (xr & 7) << 4;
                bf16x8 af[8];
                #pragma unroll
                for (int j = 0; j < 8; ++j)
                    af[j] = *(const bf16x8*)((const char*)xs +
                             ((xr * 512 + (j * 32 + q * 8) * 2) ^ xswz));
                #pragma unroll
                for (int j = 0; j < 8; ++j) {
                    accA[rtile] = __builtin_amdgcn_mfma_f32_16x16x32_bf16(af[j], wA[j], accA[rtile], 0, 0, 0);
                    accB[rtile] = __builtin_amdgcn_mfma_f32_16x16x32_bf16(af[j], wB[j], accB[rtile], 0, 0, 0);
                }
            }
        }
        const float bA = sbias[ct0 * 16 + n];
        const float bB = sbias[(ct0 + 1) * 16 + n];
        #pragma unroll
        for (int rtile = 0; rtile < 5; ++rtile)
            #pragma unroll
            for (int idx = 0; idx < 4; ++idx) {
                const int row = rtile * 16 + q * 4 + idx;     // 0..79
                const int growh = t0 - 8 + row;
                const int rswz = (row & 7) << 4;
                const bool ok = (growh >= 0 && growh < l);
                *(unsigned short*)((char*)hs +
                    ((row * 512 + (ct0 * 16 + n) * 2) ^ rswz)) =
                        ok ? f2b_(accA[rtile][idx] + bA) : (unsigned short)0;
                *(unsigned short*)((char*)hs +
                    ((row * 512 + ((ct0 + 1) * 16 + n) * 2) ^ rswz)) =
                        ok ? f2b_(accB[rtile][idx] + bB) : (unsigned short)0;
            }
        __syncthreads();   // hs computed (xs now dead -> qs/ks may overwrite)
    } else {
        // ---- stage H halo (80 rows x 256 ch); source pre-swizzled ----
        #pragma unroll
        for (int i = 0; i < 5; ++i) {
            const int task = i * 512 + tid;
            const int r = task >> 5, ch = task & 31;
            const int grow = t0 - 8 + r;
            const unsigned short* src = (grow >= 0 && grow < l)
                ? h16in + (seqbase + grow) * 256 + ((ch ^ (r & 7)) << 3)
                : x16g;                           // 512 B of zeros (guard)
            __builtin_amdgcn_global_load_lds(
                (const __attribute__((address_space(1))) void*)src,
                (__attribute__((address_space(3))) void*)
                    (hs + (size_t)(i * 512 + (tid & ~63)) * 8),
                16, 0, 0);
        }
        __syncthreads();
    }

    // ======== phase A: project q,k — wave owns col-tiles {2w, 2w+1} ========
    {   // ---- q (weight rows 0..255) -> qs rows 0..63 ----
        bf16x8 bwa[8], bwb[8];
        const unsigned short* wa_ = qw + (size_t)(ct0 * 16 + n) * 256 + q * 8;
        const unsigned short* wb_ = qw + (size_t)((ct0 + 1) * 16 + n) * 256 + q * 8;
        #pragma unroll
        for (int j = 0; j < 8; ++j) {
            bwa[j] = *(const bf16x8*)(wa_ + j * 32);
            bwb[j] = *(const bf16x8*)(wb_ + j * 32);
        }
        #pragma unroll
        for (int rtq = 0; rtq < 4; ++rtq) {
            const int hr = 8 + rtq * 16 + n;
            const int hswz = (hr & 7) << 4;
            bf16x8 af[8];
            #pragma unroll
            for (int j = 0; j < 8; ++j)
                af[j] = *(const bf16x8*)((const char*)hs +
                         ((hr * 512 + (j * 32 + q * 8) * 2) ^ hswz));
            f32x4 aA = {}, aB = {};
            #pragma unroll
            for (int j = 0; j < 8; ++j) {
                aA = __builtin_amdgcn_mfma_f32_16x16x32_bf16(af[j], bwa[j], aA, 0, 0, 0);
                aB = __builtin_amdgcn_mfma_f32_16x16x32_bf16(af[j], bwb[j], aB, 0, 0, 0);
            }
            #pragma unroll
            for (int idx = 0; idx < 4; ++idx) {
                const int row = rtq * 16 + q * 4 + idx;
                const int rswz = (row & 7) << 4;
                *(unsigned short*)((char*)qs +
                    ((row * 512 + (ct0 * 16 + n) * 2) ^ rswz)) = f2b_(aA[idx]);
                *(unsigned short*)((char*)qs +
                    ((row * 512 + ((ct0 + 1) * 16 + n) * 2) ^ rswz)) = f2b_(aB[idx]);
            }
        }
    }
    {   // ---- k (weight rows 256..511) -> ks halo rows 0..79 ----
        bf16x8 bwa[8], bwb[8];
        const unsigned short* wa_ = qw + (size_t)(256 + ct0 * 16 + n) * 256 + q * 8;
        const unsigned short* wb_ = qw + (size_t)(256 + (ct0 + 1) * 16 + n) * 256 + q * 8;
        #pragma unroll
        for (int j = 0; j < 8; ++j) {
            bwa[j] = *(const bf16x8*)(wa_ + j * 32);
            bwb[j] = *(const bf16x8*)(wb_ + j * 32);
        }
        #pragma unroll
        for (int rtk = 0; rtk < 5; ++rtk) {
            const int hr = rtk * 16 + n;
            const int hswz = (hr & 7) << 4;
            bf16x8 af[8];
            #pragma unroll
            for (int j = 0; j < 8; ++j)
                af[j] = *(const bf16x8*)((const char*)hs +
                         ((hr * 512 + (j * 32 + q * 8) * 2) ^ hswz));
            f32x4 aA = {}, aB = {};
            #pragma unroll
            for (int j = 0; j < 8; ++j) {
                aA = __builtin_amdgcn_mfma_f32_16x16x32_bf16(af[j], bwa[j], aA, 0, 0, 0);
                aB = __builtin_amdgcn_mfma_f32_16x16x32_bf16(af[j], bwb[j], aB, 0, 0, 0);
            }
            #pragma unroll
            for (int idx = 0; idx < 4; ++idx) {
                const int row = rtk * 16 + q * 4 + idx;
                const int rswz = (row & 7) << 4;
                *(unsigned short*)((char*)ks +
                    ((row * 512 + (ct0 * 16 + n) * 2) ^ rswz)) = f2b_(aA[idx]);
                *(unsigned short*)((char*)ks +
                    ((row * 512 + ((ct0 + 1) * 16 + n) * 2) ^ rswz)) = f2b_(aB[idx]);
            }
        }
    }
    __syncthreads();   // qs/ks fully written

    // ======== width head partial (32 channels per lane, from hs) ========
    const int kc0 = half * 128;
    float wdot = 0.0f;
    {
        const int hr = 8 + rt * 16 + n;
        const int hswz = (hr & 7) << 4;
        #pragma unroll
        for (int jj = 0; jj < 4; ++jj) {
            bf16x8 hv = *(const bf16x8*)((const char*)hs +
                        ((hr * 512 + (kc0 + q * 32 + jj * 8) * 2) ^ hswz));
            float4 wa = *((const float4*)(ww + kc0 + q * 32 + jj * 8));
            float4 wc = *((const float4*)(ww + kc0 + q * 32 + jj * 8 + 4));
            wdot += bf2f_((unsigned short)hv[0]) * wa.x
                  + bf2f_((unsigned short)hv[1]) * wa.y
                  + bf2f_((unsigned short)hv[2]) * wa.z
                  + bf2f_((unsigned short)hv[3]) * wa.w
                  + bf2f_((unsigned short)hv[4]) * wc.x
                  + bf2f_((unsigned short)hv[5]) * wc.y
                  + bf2f_((unsigned short)hv[6]) * wc.z
                  + bf2f_((unsigned short)hv[7]) * wc.w;
        }
    }
    wdot += __shfl_xor(wdot, 16, 64);
    wdot += __shfl_xor(wdot, 32, 64);
    if (half == 1 && q == 0) ws1[rt * 16 + n] = wdot;

    // ======== QK^T partial from LDS (4 k-chunks of this half) ========
    f32x4 accS[2] = {};
    {
        const int qrow = rt * 16 + n;
        const int qswz = (qrow & 7) << 4;
        bf16x8 qf[4];
        #pragma unroll
        for (int j = 0; j < 4; ++j)
            qf[j] = *(const bf16x8*)((const char*)qs +
                     ((qrow * 512 + (kc0 + q * 8 + j * 32) * 2) ^ qswz));
        #pragma unroll
        for (int h = 0; h < 2; ++h) {
            const int rk = rt * 16 + h * 16 + n;
            const int kswz = (rk & 7) << 4;
            #pragma unroll
            for (int j = 0; j < 4; ++j) {
                bf16x8 kb = *(const bf16x8*)((const char*)ks +
                            ((rk * 512 + (kc0 + q * 8 + j * 32) * 2) ^ kswz));
                accS[h] = __builtin_amdgcn_mfma_f32_16x16x32_bf16(
                    qf[j], kb, accS[h], 0, 0, 0);
            }
        }
    }
    if (half == 1) {
        *(f32x4*)(sp1 + ((rt * 2 + 0) * 64 + lane) * 4) = accS[0];
        *(f32x4*)(sp1 + ((rt * 2 + 1) * 64 + lane) * 4) = accS[1];
    }
    __syncthreads();   // sp1 + ws1 staged; qs/ks reads complete

    if (half == 0) {
        accS[0] += *(const f32x4*)(sp1 + ((rt * 2 + 0) * 64 + lane) * 4);
        accS[1] += *(const f32x4*)(sp1 + ((rt * 2 + 1) * 64 + lane) * 4);
        const float w_n = sigmoidf_(wdot + ws1[rt * 16 + n] + wbp[0]) * 8.0f + 0.5f;

        float wd[4];
        #pragma unroll
        for (int r = 0; r < 4; ++r) wd[r] = __shfl(w_n, q * 4 + r, 64);

        float s[2][4];
        #pragma unroll
        for (int h = 0; h < 2; ++h)
            #pragma unroll
            for (int r = 0; r < 4; ++r) {
                int ii = q * 4 + r;
                int c  = h * 16 + n;
                int w  = c - ii;
                float dist = fabsf((float)w - 8.0f);
                float sm = sigmoidf_((wd[r] - dist) * 5.0f);
                float v = accS[h][r] * 0.0625f - (1.0f - sm) * 10000.0f;
                s[h][r] = (w >= 0 && w <= 16) ? v : -3.0e38f;
            }

        float mx[4], sum[4];
        #pragma unroll
        for (int r = 0; r < 4; ++r) mx[r] = fmaxf(s[0][r], s[1][r]);
        #pragma unroll
        for (int m = 1; m < 16; m <<= 1)
            #pragma unroll
            for (int r = 0; r < 4; ++r) mx[r] = fmaxf(mx[r], __shfl_xor(mx[r], m, 64));
        float e[2][4];
        #pragma unroll
        for (int h = 0; h < 2; ++h)
            #pragma unroll
            for (int r = 0; r < 4; ++r) e[h][r] = expf(s[h][r] - mx[r]);
        #pragma unroll
        for (int r = 0; r < 4; ++r) sum[r] = e[0][r] + e[1][r];
        #pragma unroll
        for (int m = 1; m < 16; m <<= 1)
            #pragma unroll
            for (int r = 0; r < 4; ++r) sum[r] += __shfl_xor(sum[r], m, 64);

        // write P (bf16), folding the +Vp[t] residual: +1 at center c == ii+8
        #pragma unroll
        for (int h = 0; h < 2; ++h)
            #pragma unroll
            for (int r = 0; r < 4; ++r) {
                int ii = q * 4 + r, c = h * 16 + n;
                float p = e[h][r] / sum[r];
                if (c == ii + 8) p += 1.0f;
                pb[rt * 512 + ii * 32 + c] = f2b_(p);
            }
    }
    __syncthreads();   // pb ready; qs/ks now dead -> vt may overwrite

    // ======== phase B: project Vp (weight rows 512..767) into vt ========
    {
        bf16x8 bwa[8], bwb[8];
        const unsigned short* wa_ = qw + (size_t)(512 + ct0 * 16 + n) * 256 + q * 8;
        const unsigned short* wb_ = qw + (size_t)(512 + (ct0 + 1) * 16 + n) * 256 + q * 8;
        #pragma unroll
        for (int j = 0; j < 8; ++j) {
            bwa[j] = *(const bf16x8*)(wa_ + j * 32);
            bwb[j] = *(const bf16x8*)(wb_ + j * 32);
        }
        #pragma unroll
        for (int rtv = 0; rtv < 5; ++rtv) {
            const int hr = rtv * 16 + n;
            const int hswz = (hr & 7) << 4;
            bf16x8 af[8];
            #pragma unroll
            for (int j = 0; j < 8; ++j)
                af[j] = *(const bf16x8*)((const char*)hs +
                         ((hr * 512 + (j * 32 + q * 8) * 2) ^ hswz));
            f32x4 aA = {}, aB = {};
            #pragma unroll
            for (int j = 0; j < 8; ++j) {
                aA = __builtin_amdgcn_mfma_f32_16x16x32_bf16(af[j], bwa[j], aA, 0, 0, 0);
                aB = __builtin_amdgcn_mfma_f32_16x16x32_bf16(af[j], bwb[j], aB, 0, 0, 0);
            }
            // Vt[c][r]: 4 consecutive r per lane -> one 8 B store per ct
            ushort4 pA, pB;
            pA.x = f2b_(aA[0]); pA.y = f2b_(aA[1]); pA.z = f2b_(aA[2]); pA.w = f2b_(aA[3]);
            pB.x = f2b_(aB[0]); pB.y = f2b_(aB[1]); pB.z = f2b_(aB[2]); pB.w = f2b_(aB[3]);
            const int rb = rtv * 16 + q * 4;
            *(ushort4*)(vt + (size_t)(ct0 * 16 + n) * 88 + rb) = pA;
            *(ushort4*)(vt + (size_t)((ct0 + 1) * 16 + n) * 88 + rb) = pB;
        }
    }
    __syncthreads();   // vt ready

    // ======== PV: this wave handles ct = half*8 .. half*8+7 ========
    bf16x8 pf = *(const bf16x8*)(pb + rt * 512 + n * 32 + q * 8);
    const int rl = q * 4;                       // even
    const size_t gbase = seqbase + row0;
    #pragma unroll
    for (int c = 0; c < 8; ++c) {
        const int ct = half * 8 + c;
        bf16x8 vf = *(const bf16x8*)(vt + (ct * 16 + n) * 88 + rt * 16 + q * 8);
        f32x4 z = {};
        f32x4 o = __builtin_amdgcn_mfma_f32_16x16x32_bf16(pf, vf, z, 0, 0, 0);
        const int col = ct * 16 + n;
        float v0 = o[0], v1 = o[1], v2 = o[2], v3 = o[3];
        size_t r0 = (gbase + rl) * CH + col;
        l16o[r0]          = f2b_(v0);
        l16o[r0 + CH]     = f2b_(v1);
        l16o[r0 + 2 * CH] = f2b_(v2);
        l16o[r0 + 3 * CH] = f2b_(v3);
        if (dsB) {
            size_t d0 = ((gbase + rl) >> 1) * CH + col;
            dsB[d0]      = f2b_(0.5f * (v0 + v1));
            dsB[d0 + CH] = f2b_(0.5f * (v2 + v3));
        }
    }
}

// ---------------------------------------------------------------------------
// Fused global-attention tail: per block (chunk of 128 t's, batch b):
//   pass 1: e[t] = exp(concat[t]·query)  (unnormalized softmax — |s| small)
//   pass 2: partials[d] = sum_t e[t]*concat[t][d]; denomP = sum_t e[t]
// grid (64, B), block 1024.
// ---------------------------------------------------------------------------
__global__ __launch_bounds__(1024) void tail_ctx_kernel(
    const unsigned short* __restrict__ l0, const unsigned short* __restrict__ l1,
    const unsigned short* __restrict__ l2, const unsigned short* __restrict__ l3,
    const float* __restrict__ query, float* __restrict__ partials,
    float* __restrict__ denomP)
{
    __shared__ float eS[128];
    const int tid = threadIdx.x;
    const int chunk = blockIdx.x, b = blockIdx.y;
    const int t0 = chunk * 128;
    const unsigned short* levp[4] = {l0, l1, l2, l3};

    // ---- pass 1: wave w computes e for t = t0 + w*8 + j ----
    const int w = tid >> 6, lane = tid & 63;
    const int lev = lane >> 4, c0 = (lane & 15) * 16;
    const unsigned short* lpbase = levp[lev] + (size_t)b * (L_SEQ >> lev) * CH;
    const float* qp = query + lev * CH + c0;
    float4 q0 = *(const float4*)(qp);
    float4 q1 = *(const float4*)(qp + 4);
    float4 q2 = *(const float4*)(qp + 8);
    float4 q3 = *(const float4*)(qp + 12);
    #pragma unroll
    for (int j = 0; j < 8; ++j) {
        int t = t0 + w * 8 + j;
        const unsigned short* p = lpbase + (size_t)(t >> lev) * CH + c0;
        float4 h0 = ldb4_(p), h1 = ldb4_(p + 4), h2 = ldb4_(p + 8), h3 = ldb4_(p + 12);
        float part = h0.x * q0.x + h0.y * q0.y + h0.z * q0.z + h0.w * q0.w
                   + h1.x * q1.x + h1.y * q1.y + h1.z * q1.z + h1.w * q1.w
                   + h2.x * q2.x + h2.y * q2.y + h2.z * q2.z + h2.w * q2.w
                   + h3.x * q3.x + h3.y * q3.y + h3.z * q3.z + h3.w * q3.w;
        #pragma unroll
        for (int m = 1; m < 64; m <<= 1) part += __shfl_xor(part, m, 64);
        if (lane == 0) eS[w * 8 + j] = expf(part);
    }
    __syncthreads();

    if (tid == 0) {
        float ds = 0.0f;
        #pragma unroll 8
        for (int i = 0; i < 128; ++i) ds += eS[i];
        denomP[b * 64 + chunk] = ds;
    }

    // ---- pass 2: weighted accumulation (rows are L2-hot from pass 1) ----
    const int dlev = tid >> 8, c = tid & 255;
    const unsigned short* lp = levp[dlev] + (size_t)b * (L_SEQ >> dlev) * CH;
    float acc = 0.0f;
    #pragma unroll 4
    for (int t = t0; t < t0 + 128; ++t)
        acc += eS[t - t0] * bf2f_(lp[(size_t)(t >> dlev) * CH + c]);
    partials[(size_t)(b * 64 + chunk) * 1024 + tid] = acc;
}

// ---------------------------------------------------------------------------
// film kernel with the ctx reduction folded in: each block cooperatively
// recomputes ctx (ascending-chunk sum / denom — bitwise-identical to the old
// ctx_reduce) into LDS, then runs the unchanged film math from LDS.
// grid 128, block 256 (4 waves, one j per wave).
// ---------------------------------------------------------------------------
__global__ __launch_bounds__(256) void film_kernel(
    const float* __restrict__ partials, const float* __restrict__ denomP,
    const float* __restrict__ fw, const float* __restrict__ fb,
    float* __restrict__ film)
{
    __shared__ float ctxS[2048];
    const int tid = threadIdx.x;

    float den[2];
    #pragma unroll
    for (int b = 0; b < 2; ++b) {
        float d = 0.0f;
        #pragma unroll
        for (int c = 0; c < 64; ++c) d += denomP[b * 64 + c];
        den[b] = d;
    }
    #pragma unroll
    for (int v = 0; v < 8; ++v) {
        const int idx = v * 256 + tid;            // 0..2047
        const int b = idx >> 10, d = idx & 1023;
        float acc = 0.0f;
        #pragma unroll
        for (int c = 0; c < 64; ++c)
            acc += partials[(size_t)(b * 64 + c) * 1024 + d];
        ctxS[idx] = acc / den[b];
    }
    __syncthreads();

    const int lane = tid & 63;
    const int j = blockIdx.x * 4 + (tid >> 6);    // 0..511
    float acc0 = 0.0f, acc1 = 0.0f;
    #pragma unroll
    for (int r = 0; r < 4; ++r) {
        float4 w4 = *((const float4*)(fw + (size_t)j * 1024 + r * 256) + lane);
        float4 c0 = *((const float4*)(ctxS + r * 256) + lane);
        float4 c1 = *((const float4*)(ctxS + 1024 + r * 256) + lane);
        acc0 += w4.x * c0.x + w4.y * c0.y + w4.z * c0.z + w4.w * c0.w;
        acc1 += w4.x * c1.x + w4.y * c1.y + w4.z * c1.z + w4.w * c1.w;
    }
    #pragma unroll
    for (int m = 1; m < 64; m <<= 1) {
        acc0 += __shfl_xor(acc0, m, 64);
        acc1 += __shfl_xor(acc1, m, 64);
    }
    if (lane == 0) {
        float b = fb[j];
        film[j] = acc0 + b;
        film[512 + j] = acc1 + b;
    }
}

// out = l16_0 * (1 + scale_f) + bias_f, 4 elem/thread (ushort4 -> float4)
__global__ void final_kernel(const unsigned short* __restrict__ lev0,
                             const float* __restrict__ film,
                             float* __restrict__ out)
{
    size_t n4 = ((size_t)blockIdx.x * 256 + threadIdx.x) * 4;
    int c = (int)(n4 & (CH - 1));
    int b = (int)(n4 >> 21);  // L*C = 2^21
    float4 h = ldb4_(lev0 + n4);
    const float* fs = film + b * 512;
    float4 o;
    o.x = h.x * (1.0f + fs[c + 0]) + fs[256 + c + 0];
    o.y = h.y * (1.0f + fs[c + 1]) + fs[256 + c + 1];
    o.z = h.z * (1.0f + fs[c + 2]) + fs[256 + c + 2];
    o.w = h.w * (1.0f + fs[c + 3]) + fs[256 + c + 3];
    *(float4*)(out + n4) = o;
}

extern "C" void kernel_launch(void* const* d_in, const int* in_sizes, int n_in,
                              void* d_out, int out_size, void* d_ws, size_t ws_size,
                              hipStream_t stream) {
    const float* x       = (const float*)d_in[0];
    const float* stem_w  = (const float*)d_in[1];
    const float* stem_b  = (const float*)d_in[2];
    const float* qkv_w   = (const float*)d_in[3];
    const float* width_w = (const float*)d_in[4];
    const float* width_b = (const float*)d_in[5];
    const float* out_w   = (const float*)d_in[6];
    const float* query   = (const float*)d_in[7];
    const float* film_w  = (const float*)d_in[8];
    const float* film_b  = (const float*)d_in[9];
    float* out = (float*)d_out;
    float* ws  = (float*)d_ws;

    // ---- workspace layout (fp32 region then bf16 region) ----
    float* partials = ws;                       // 131,072
    float* denomP   = partials + 131072;        // 128
    float* ctx      = denomP + 128;             // 2,048 (unused)
    float* film     = ctx + 2048;               // 1,024
    unsigned short* x16g  = (unsigned short*)(film + 1024);  // 256 guard + 4,194,304
    unsigned short* h16_0 = x16g + 4194560;     // 4,194,304 (unused now)
    unsigned short* h16_1 = h16_0 + 4194304;    // 2,097,152
    unsigned short* h16_2 = h16_1 + 2097152;    // 1,048,576
    unsigned short* h16_3 = h16_2 + 1048576;    //   524,288
    unsigned short* qkv16 = h16_3 + 524288;     // 12,582,912 (reserved, unused)
    unsigned short* ov16  = qkv16 + 12582912;   // 4,194,304 (reserved, unused)
    unsigned short* l16_0 = ov16 + 4194304;     // 4,194,304
    unsigned short* l16_1 = l16_0 + 4194304;    // 2,097,152
    unsigned short* l16_2 = l16_1 + 2097152;    // 1,048,576
    unsigned short* l16_3 = l16_2 + 1048576;    //   524,288
    unsigned short* qw16  = l16_3 + 524288;     //   196,608
    unsigned short* ow16  = qw16 + 196608;      //    65,536 (reserved, unused)
    unsigned short* sw16  = ow16 + 65536;       //   131,072
    unsigned short* h16[4]  = {h16_0, h16_1, h16_2, h16_3};
    unsigned short* l16[4]  = {l16_0, l16_1, l16_2, l16_3};
    (void)qkv16; (void)ov16; (void)ow16; (void)ctx;

    // ---- fused prep (guard + x16 + q/k weights + stem) + Vp weight fold ----
    prep_kernel<<<NPREP_BLOCKS + 256, 256, 0, stream>>>(
        x, qkv_w, out_w, stem_w, x16g, qw16, sw16);

    // ---- hierarchy levels: ONE fused kernel per level; level 0 also
    //      computes the stem conv in-block (STEM=1) ----
    for (int i = 0; i < NLEV; ++i) {
        const int l = L_SEQ >> i;
        const int M = B_SZ * l;
        if (i == 0)
            level_fused_kernel<1><<<M / 64, 512, 0, stream>>>(
                h16[0], x16g, sw16, stem_b, qw16, width_w, width_b,
                l16[0], h16_1, l);
        else
            level_fused_kernel<0><<<M / 64, 512, 0, stream>>>(
                h16[i], x16g, sw16, stem_b, qw16, width_w, width_b,
                l16[i], (i < NLEV - 1) ? h16[i + 1] : nullptr, l);
    }

    // ---- fused global-attention tail + FiLM (ctx reduction folded in) ----
    tail_ctx_kernel<<<dim3(64, B_SZ), 1024, 0, stream>>>(
        l16_0, l16_1, l16_2, l16_3, query, partials, denomP);
    film_kernel<<<128, 256, 0, stream>>>(partials, denomP, film_w, film_b, film);
    final_kernel<<<(B_SZ * L_SEQ * CH) / 1024, 256, 0, stream>>>(l16_0, film, out);
}